// Round 7
// baseline (419.566 us; speedup 1.0000x reference)
//
#include <hip/hip_runtime.h>
#include <hip/hip_bf16.h>
#include <hip/hip_fp16.h>

#define NNODES 50000
#define NEG_SLOPE 0.2f
#define BKT_SHIFT 8
#define NBKT ((NNODES + 255) >> 8)   // 196 buckets of 256 dsts

__device__ __forceinline__ int rfl(int v) { return __builtin_amdgcn_readfirstlane(v); }

// ---------------- CSR build ----------------

// per-dst degree (global atomics) + per-bucket histogram (LDS privatized)
__global__ void count_deg_hist(const int* __restrict__ dst, int* __restrict__ deg,
                               int* __restrict__ bhist, int E) {
    __shared__ int lh[NBKT];
    for (int i = threadIdx.x; i < NBKT; i += 256) lh[i] = 0;
    __syncthreads();
    for (int i = blockIdx.x * 256 + threadIdx.x; i < E; i += gridDim.x * 256) {
        int d = dst[i];
        atomicAdd(&deg[d], 1);
        atomicAdd(&lh[d >> BKT_SHIFT], 1);
    }
    __syncthreads();
    for (int i = threadIdx.x; i < NBKT; i += 256)
        if (lh[i]) atomicAdd(&bhist[i], lh[i]);
}

__global__ void scan_partial(const int* __restrict__ deg, int* __restrict__ blocksum, int N) {
    int i = blockIdx.x * 256 + threadIdx.x;
    int v = (i < N) ? deg[i] : 0;
#pragma unroll
    for (int m = 1; m < 64; m <<= 1) v += __shfl_xor(v, m, 64);
    __shared__ int ws[4];
    if ((threadIdx.x & 63) == 0) ws[threadIdx.x >> 6] = v;
    __syncthreads();
    if (threadIdx.x == 0) blocksum[blockIdx.x] = ws[0] + ws[1] + ws[2] + ws[3];
}

__global__ void scan_blocksums(int* __restrict__ blocksum, int nb) {
    __shared__ int buf[256];
    int t = threadIdx.x;
    int v = (t < nb) ? blocksum[t] : 0;
    buf[t] = v;
    __syncthreads();
    for (int off = 1; off < 256; off <<= 1) {
        int x = (t >= off) ? buf[t - off] : 0;
        __syncthreads();
        buf[t] += x;
        __syncthreads();
    }
    if (t < nb) blocksum[t] = buf[t] - v;  // exclusive
}

__global__ void scan_final(const int* __restrict__ deg, const int* __restrict__ blocksum,
                           int* __restrict__ rowptr, int N, int E) {
    int i = blockIdx.x * 256 + threadIdx.x;
    int lane = threadIdx.x & 63;
    int v = (i < N) ? deg[i] : 0;
    int x = v;
#pragma unroll
    for (int m = 1; m < 64; m <<= 1) {
        int y = __shfl_up(x, m, 64);
        if (lane >= m) x += y;
    }
    __shared__ int ws[4];
    if (lane == 63) ws[threadIdx.x >> 6] = x;
    __syncthreads();
    int w = threadIdx.x >> 6;
    int waveoff = 0;
#pragma unroll
    for (int k = 0; k < 4; k++) if (k < w) waveoff += ws[k];
    int excl = blocksum[blockIdx.x] + waveoff + x - v;
    if (i < N) rowptr[i] = excl;
    if (i == N - 1) rowptr[N] = E;
}

// exclusive scan of the 196 bucket counts; init padded cursors (64 B apart)
__global__ void scan_buckets(const int* __restrict__ bhist, int* __restrict__ bbase,
                             int* __restrict__ bcursor) {
    __shared__ int buf[256];
    int t = threadIdx.x;
    int v = (t < NBKT) ? bhist[t] : 0;
    buf[t] = v;
    __syncthreads();
    for (int off = 1; off < 256; off <<= 1) {
        int x = (t >= off) ? buf[t - off] : 0;
        __syncthreads();
        buf[t] += x;
        __syncthreads();
    }
    if (t < NBKT) { int e = buf[t] - v; bbase[t] = e; bcursor[t * 16] = e; }
}

// scatter edges into bucket-grouped regions (writes dense within ~32 KB windows)
__global__ void scatter_bucket(const int* __restrict__ src, const int* __restrict__ dst,
                               int* __restrict__ bcursor, int2* __restrict__ ebuf, int E) {
    int i = blockIdx.x * 256 + threadIdx.x;
    if (i < E) {
        int d = dst[i];
        int p = atomicAdd(&bcursor[(d >> BKT_SHIFT) * 16], 1);
        ebuf[p] = make_int2(src[i], d);
    }
}

// one block per bucket: place each edge at rowptr[d] + rank (LDS cursors)
__global__ __launch_bounds__(256) void local_sort(const int2* __restrict__ ebuf,
                                                  const int* __restrict__ bbase,
                                                  const int* __restrict__ rowptr,
                                                  int* __restrict__ csrc, int E) {
    __shared__ int lrow[256], lcur[256];
    int b = blockIdx.x;
    int d0 = b << BKT_SHIFT;
    int nd = min(256, NNODES - d0);
    int t = threadIdx.x;
    if (t < nd) lrow[t] = rowptr[d0 + t];
    lcur[t] = 0;
    __syncthreads();
    int beg = bbase[b];
    int end = (b + 1 < NBKT) ? bbase[b + 1] : E;
    for (int i = beg + t; i < end; i += 256) {
        int2 e = ebuf[i];
        int ld = e.y - d0;
        int p = lrow[ld] + atomicAdd(&lcur[ld], 1);
        csrc[p] = e.x;
    }
}

// ---------------- GEMM + attention logits (W in VGPRs, float4 x loads) ----------------
template <int K>
__global__ __launch_bounds__(256, 2) void gemm32(
    const float* __restrict__ X, const float* __restrict__ W,
    const float* __restrict__ AL, const float* __restrict__ AR,
    __half* __restrict__ feat16, float* __restrict__ el, float* __restrict__ er, int N) {
    int wave = threadIdx.x >> 6, lane = threadIdx.x & 63;
    float w[K];
#pragma unroll
    for (int k = 0; k < K; k++) w[k] = W[k * 64 + lane];
    float alv = AL[lane], arv = AR[lane];
    for (int n0 = blockIdx.x * 4 + wave; n0 < N; n0 += gridDim.x * 4) {
        int n = rfl(n0);
        const float4* __restrict__ x4 = (const float4*)(X + (size_t)n * K);
        float acc = 0.f;
#pragma unroll
        for (int k4 = 0; k4 < K / 4; k4++) {
            float4 xv = x4[k4];
            acc = fmaf(xv.x, w[4 * k4 + 0], acc);
            acc = fmaf(xv.y, w[4 * k4 + 1], acc);
            acc = fmaf(xv.z, w[4 * k4 + 2], acc);
            acc = fmaf(xv.w, w[4 * k4 + 3], acc);
        }
        feat16[(size_t)n * 64 + lane] = __float2half(acc);
        float vl = acc * alv, vr = acc * arv;
#pragma unroll
        for (int m = 1; m < 32; m <<= 1) {
            vl += __shfl_xor(vl, m, 64);
            vr += __shfl_xor(vr, m, 64);
        }
        if ((lane & 31) == 0) {
            int h = lane >> 5;
            el[n * 2 + h] = vl;
            er[n * 2 + h] = vr;
        }
    }
}

__global__ __launch_bounds__(256, 2) void gemm64(
    const float* __restrict__ X, const float* __restrict__ W,
    const float* __restrict__ AL, const float* __restrict__ AR,
    __half2* __restrict__ feat2, float* __restrict__ el, float* __restrict__ er, int N) {
    int wave = threadIdx.x >> 6, d = threadIdx.x & 63;
    float w0[64], w1[64];
#pragma unroll
    for (int k = 0; k < 64; k++) {
        w0[k] = W[k * 128 + d];
        w1[k] = W[k * 128 + 64 + d];
    }
    float al0 = AL[d], al1 = AL[64 + d], ar0 = AR[d], ar1 = AR[64 + d];
    for (int n0 = blockIdx.x * 4 + wave; n0 < N; n0 += gridDim.x * 4) {
        int n = rfl(n0);
        const float4* __restrict__ x4 = (const float4*)(X + (size_t)n * 64);
        float a0 = 0.f, a1 = 0.f;
#pragma unroll
        for (int k4 = 0; k4 < 16; k4++) {
            float4 xv = x4[k4];
            a0 = fmaf(xv.x, w0[4 * k4 + 0], a0); a1 = fmaf(xv.x, w1[4 * k4 + 0], a1);
            a0 = fmaf(xv.y, w0[4 * k4 + 1], a0); a1 = fmaf(xv.y, w1[4 * k4 + 1], a1);
            a0 = fmaf(xv.z, w0[4 * k4 + 2], a0); a1 = fmaf(xv.z, w1[4 * k4 + 2], a1);
            a0 = fmaf(xv.w, w0[4 * k4 + 3], a0); a1 = fmaf(xv.w, w1[4 * k4 + 3], a1);
        }
        feat2[(size_t)n * 64 + d] = __floats2half2_rn(a0, a1);
        float l0 = a0 * al0, r0 = a0 * ar0;
        float l1 = a1 * al1, r1 = a1 * ar1;
#pragma unroll
        for (int m = 1; m < 64; m <<= 1) {
            l0 += __shfl_xor(l0, m, 64);
            r0 += __shfl_xor(r0, m, 64);
            l1 += __shfl_xor(l1, m, 64);
            r1 += __shfl_xor(r1, m, 64);
        }
        if (d == 0) {
            el[n * 2 + 0] = l0; el[n * 2 + 1] = l1;
            er[n * 2 + 0] = r0; er[n * 2 + 1] = r1;
        }
    }
}

// ---------------- Aggregation (fused edge weights, unroll x8) ----------------
// NOTE: every __shfl executes with FULL exec mask; head-select AFTER broadcast.
template <bool RELU>
__global__ __launch_bounds__(256) void aggregate32(
    const int* __restrict__ rowptr, const int* __restrict__ csrc,
    const float2* __restrict__ el2, const float2* __restrict__ er2,
    const __half* __restrict__ feat16, const float* __restrict__ b,
    float* __restrict__ out, int N) {
    int wave = threadIdx.x >> 6, lane = threadIdx.x & 63, h = lane >> 5;
    int n = rfl(blockIdx.x * 4 + wave);
    if (n >= N) return;
    float bl = b[lane];
    int beg = rfl(rowptr[n]), end = rfl(rowptr[n + 1]);
    float2 rr = er2[n];
    float s = 0.f, acc = 0.f;
    for (int base = beg; base < end; base += 64) {
        int idx = base + lane;
        int sv = 0; float wxv = 0.f, wyv = 0.f;
        if (idx < end) {
            sv = csrc[idx];
            float2 l = el2[sv];
            float t0 = l.x + rr.x; t0 = t0 > 0.f ? t0 : NEG_SLOPE * t0;
            float t1 = l.y + rr.y; t1 = t1 > 0.f ? t1 : NEG_SLOPE * t1;
            wxv = __expf(t0); wyv = __expf(t1);
        }
        int cnt = min(64, end - base);
        int j = 0;
        for (; j + 7 < cnt; j += 8) {
            float fv[8], wv[8];
#pragma unroll
            for (int u = 0; u < 8; u++) {
                int su = __shfl(sv, j + u, 64);
                float wxu = __shfl(wxv, j + u, 64);
                float wyu = __shfl(wyv, j + u, 64);
                wv[u] = h ? wyu : wxu;
                fv[u] = __half2float(feat16[(size_t)su * 64 + lane]);
            }
#pragma unroll
            for (int u = 0; u < 8; u++) {
                s += wv[u];
                acc = fmaf(wv[u], fv[u], acc);
            }
        }
        for (; j < cnt; j++) {
            int s0 = __shfl(sv, j, 64);
            float wx0 = __shfl(wxv, j, 64), wy0 = __shfl(wyv, j, 64);
            float w0 = h ? wy0 : wx0;
            float f0 = __half2float(feat16[(size_t)s0 * 64 + lane]);
            s += w0;
            acc = fmaf(w0, f0, acc);
        }
    }
    float v = (s > 0.f) ? acc / s : 0.f;
    v += bl;
    if (RELU) v = fmaxf(v, 0.f);
    out[(size_t)n * 64 + lane] = v;
}

__global__ __launch_bounds__(256) void aggregate64_mean(
    const int* __restrict__ rowptr, const int* __restrict__ csrc,
    const float2* __restrict__ el2, const float2* __restrict__ er2,
    const __half2* __restrict__ feat2, const float* __restrict__ b,
    float* __restrict__ out, int N) {
    int wave = threadIdx.x >> 6, lane = threadIdx.x & 63;
    int n = rfl(blockIdx.x * 4 + wave);
    if (n >= N) return;
    float b0 = b[lane], b1 = b[64 + lane];
    int beg = rfl(rowptr[n]), end = rfl(rowptr[n + 1]);
    float2 rr = er2[n];
    float s0 = 0.f, s1 = 0.f, a0 = 0.f, a1 = 0.f;
    for (int base = beg; base < end; base += 64) {
        int idx = base + lane;
        int sv = 0; float wxv = 0.f, wyv = 0.f;
        if (idx < end) {
            sv = csrc[idx];
            float2 l = el2[sv];
            float t0 = l.x + rr.x; t0 = t0 > 0.f ? t0 : NEG_SLOPE * t0;
            float t1 = l.y + rr.y; t1 = t1 > 0.f ? t1 : NEG_SLOPE * t1;
            wxv = __expf(t0); wyv = __expf(t1);
        }
        int cnt = min(64, end - base);
        int j = 0;
        for (; j + 7 < cnt; j += 8) {
            float2 fv[8]; float wxs[8], wys[8];
#pragma unroll
            for (int u = 0; u < 8; u++) {
                int eu = __shfl(sv, j + u, 64);
                wxs[u] = __shfl(wxv, j + u, 64);
                wys[u] = __shfl(wyv, j + u, 64);
                fv[u] = __half22float2(feat2[(size_t)eu * 64 + lane]);
            }
#pragma unroll
            for (int u = 0; u < 8; u++) {
                s0 += wxs[u]; s1 += wys[u];
                a0 = fmaf(wxs[u], fv[u].x, a0);
                a1 = fmaf(wys[u], fv[u].y, a1);
            }
        }
        for (; j < cnt; j++) {
            int e0 = __shfl(sv, j, 64);
            float wx0 = __shfl(wxv, j, 64), wy0 = __shfl(wyv, j, 64);
            float2 f0 = __half22float2(feat2[(size_t)e0 * 64 + lane]);
            s0 += wx0; s1 += wy0;
            a0 = fmaf(wx0, f0.x, a0); a1 = fmaf(wy0, f0.y, a1);
        }
    }
    float v0 = (s0 > 0.f) ? a0 / s0 : 0.f;
    float v1 = (s1 > 0.f) ? a1 / s1 : 0.f;
    out[(size_t)n * 64 + lane] = 0.5f * ((v0 + b0) + (v1 + b1));
}

// ---------------- launcher ----------------

extern "C" void kernel_launch(void* const* d_in, const int* in_sizes, int n_in,
                              void* d_out, int out_size, void* d_ws, size_t ws_size,
                              hipStream_t stream) {
    const float* x   = (const float*)d_in[0];
    const int*   src = (const int*)d_in[1];
    const int*   dst = (const int*)d_in[2];
    const float* W0  = (const float*)d_in[3];
    const float* al0 = (const float*)d_in[4];
    const float* ar0 = (const float*)d_in[5];
    const float* b0  = (const float*)d_in[6];
    const float* W1  = (const float*)d_in[7];
    const float* al1 = (const float*)d_in[8];
    const float* ar1 = (const float*)d_in[9];
    const float* b1  = (const float*)d_in[10];
    const float* W2  = (const float*)d_in[11];
    const float* al2 = (const float*)d_in[12];
    const float* ar2 = (const float*)d_in[13];
    const float* b2  = (const float*)d_in[14];
    float* out = (float*)d_out;

    const int N = NNODES;
    const int E = in_sizes[1];

    char* p = (char*)d_ws;
    auto alloc = [&](size_t bytes) {
        void* r = (void*)p;
        p += (bytes + 255) & ~(size_t)255;
        return r;
    };
    int*    deg      = (int*)alloc((size_t)(N + NBKT) * 4);  // deg[N] + bhist[NBKT], one memset
    int*    bhist    = deg + N;
    int*    rowptr   = (int*)alloc((size_t)(N + 1) * 4);
    int*    blocksum = (int*)alloc(256 * 4);
    int*    bbase    = (int*)alloc(NBKT * 4);
    int*    bcursor  = (int*)alloc((size_t)NBKT * 16 * 4);   // 64 B padded cursors
    int2*   ebuf     = (int2*)alloc((size_t)E * 8);
    int*    csrc     = (int*)alloc((size_t)E * 4);
    float*  el       = (float*)alloc((size_t)N * 2 * 4);
    float*  er       = (float*)alloc((size_t)N * 2 * 4);
    void*   featbuf  = alloc((size_t)N * 64 * 4);
    float*  hbuf     = (float*)alloc((size_t)N * 64 * 4);
    __half*  feat16 = (__half*)featbuf;
    __half2* feat2  = (__half2*)featbuf;
    float2* el2 = (float2*)el;
    float2* er2 = (float2*)er;

    // CSR build (graph is layer-invariant)
    hipMemsetAsync(deg, 0, (size_t)(N + NBKT) * 4, stream);
    int eb = (E + 255) / 256;
    int nb256 = (N + 255) / 256;
    count_deg_hist<<<512, 256, 0, stream>>>(dst, deg, bhist, E);
    scan_partial<<<nb256, 256, 0, stream>>>(deg, blocksum, N);
    scan_blocksums<<<1, 256, 0, stream>>>(blocksum, nb256);
    scan_final<<<nb256, 256, 0, stream>>>(deg, blocksum, rowptr, N, E);
    scan_buckets<<<1, 256, 0, stream>>>(bhist, bbase, bcursor);
    scatter_bucket<<<eb, 256, 0, stream>>>(src, dst, bcursor, ebuf, E);
    local_sort<<<NBKT, 256, 0, stream>>>(ebuf, bbase, rowptr, csrc, E);

    int nb4 = (N + 3) / 4;        // one wave per node
    int gemmGrid = 2048;          // grid-stride

    // layer 0: IN=128 -> H2xD32
    gemm32<128><<<gemmGrid, 256, 0, stream>>>(x, W0, al0, ar0, feat16, el, er, N);
    aggregate32<true><<<nb4, 256, 0, stream>>>(rowptr, csrc, el2, er2, feat16, b0, hbuf, N);

    // layer 1: 64 -> H2xD32
    gemm32<64><<<gemmGrid, 256, 0, stream>>>(hbuf, W1, al1, ar1, feat16, el, er, N);
    aggregate32<true><<<nb4, 256, 0, stream>>>(rowptr, csrc, el2, er2, feat16, b1, hbuf, N);

    // layer 2: 64 -> H2xD64, mean over heads
    gemm64<<<gemmGrid, 256, 0, stream>>>(hbuf, W2, al2, ar2, feat2, el, er, N);
    aggregate64_mean<<<nb4, 256, 0, stream>>>(rowptr, csrc, el2, er2, feat2, b2, out, N);
}

// Round 8
// 342.652 us; speedup vs baseline: 1.2245x; 1.2245x over previous
//
#include <hip/hip_runtime.h>
#include <hip/hip_bf16.h>
#include <hip/hip_fp16.h>

#define NNODES 50000
#define NEG_SLOPE 0.2f
#define BKT_SHIFT 8
#define NBKT ((NNODES + 255) >> 8)   // 196 buckets of 256 dsts
#define PEPT 8                        // partition: edges per thread

__device__ __forceinline__ int rfl(int v) { return __builtin_amdgcn_readfirstlane(v); }

// ---------------- CSR build ----------------

__global__ void count_deg(const int* __restrict__ dst, int* __restrict__ deg, int E) {
    int i = blockIdx.x * blockDim.x + threadIdx.x;
    if (i < E) atomicAdd(&deg[dst[i]], 1);
}

__global__ void scan_partial(const int* __restrict__ deg, int* __restrict__ blocksum, int N) {
    int i = blockIdx.x * 256 + threadIdx.x;
    int v = (i < N) ? deg[i] : 0;
#pragma unroll
    for (int m = 1; m < 64; m <<= 1) v += __shfl_xor(v, m, 64);
    __shared__ int ws[4];
    if ((threadIdx.x & 63) == 0) ws[threadIdx.x >> 6] = v;
    __syncthreads();
    if (threadIdx.x == 0) blocksum[blockIdx.x] = ws[0] + ws[1] + ws[2] + ws[3];
}

__global__ void scan_blocksums(int* __restrict__ blocksum, int nb) {
    __shared__ int buf[256];
    int t = threadIdx.x;
    int v = (t < nb) ? blocksum[t] : 0;
    buf[t] = v;
    __syncthreads();
    for (int off = 1; off < 256; off <<= 1) {
        int x = (t >= off) ? buf[t - off] : 0;
        __syncthreads();
        buf[t] += x;
        __syncthreads();
    }
    if (t < nb) blocksum[t] = buf[t] - v;  // exclusive
}

__global__ void scan_final(const int* __restrict__ deg, const int* __restrict__ blocksum,
                           int* __restrict__ rowptr, int N, int E) {
    int i = blockIdx.x * 256 + threadIdx.x;
    int lane = threadIdx.x & 63;
    int v = (i < N) ? deg[i] : 0;
    int x = v;
#pragma unroll
    for (int m = 1; m < 64; m <<= 1) {
        int y = __shfl_up(x, m, 64);
        if (lane >= m) x += y;
    }
    __shared__ int ws[4];
    if (lane == 63) ws[threadIdx.x >> 6] = x;
    __syncthreads();
    int w = threadIdx.x >> 6;
    int waveoff = 0;
#pragma unroll
    for (int k = 0; k < 4; k++) if (k < w) waveoff += ws[k];
    int excl = blocksum[blockIdx.x] + waveoff + x - v;
    if (i < N) rowptr[i] = excl;
    if (i == N - 1) rowptr[N] = E;
}

// bucket base = rowptr at bucket boundary (buckets are dst-aligned)
__global__ void init_bcursor(const int* __restrict__ rowptr, int* __restrict__ bcursor) {
    int t = blockIdx.x * 256 + threadIdx.x;
    if (t < NBKT) bcursor[t * 16] = rowptr[t << BKT_SHIFT];
}

// Block-privatized partition: LDS histogram gives in-block rank; ONE global
// atomic per (bucket, block) reserves a contiguous run; pass 2 fills it.
// A single block owns each run while it fills -> line-dense writebacks.
__global__ __launch_bounds__(1024) void partition_edges(
    const int* __restrict__ src, const int* __restrict__ dst,
    int* __restrict__ bcursor, int2* __restrict__ ebuf, int E) {
    __shared__ int hist[NBKT];
    __shared__ int gbase[NBKT];
    int t = threadIdx.x;
    for (int i = t; i < NBKT; i += 1024) hist[i] = 0;
    __syncthreads();
    int base = blockIdx.x * 1024 * PEPT;
    int sreg[PEPT], dreg[PEPT], rreg[PEPT], breg[PEPT];
#pragma unroll
    for (int k = 0; k < PEPT; k++) {
        int i = base + k * 1024 + t;
        if (i < E) {
            sreg[k] = src[i];
            dreg[k] = dst[i];
            breg[k] = dreg[k] >> BKT_SHIFT;
            rreg[k] = atomicAdd(&hist[breg[k]], 1);
        } else {
            breg[k] = -1;
        }
    }
    __syncthreads();
    for (int i = t; i < NBKT; i += 1024)
        if (hist[i]) gbase[i] = atomicAdd(&bcursor[i * 16], hist[i]);
    __syncthreads();
#pragma unroll
    for (int k = 0; k < PEPT; k++) {
        if (breg[k] >= 0)
            ebuf[(size_t)(gbase[breg[k]] + rreg[k])] = make_int2(sreg[k], dreg[k]);
    }
}

// one block per bucket: place each edge at rowptr[d] + rank (LDS cursors)
__global__ __launch_bounds__(256) void local_sort(const int2* __restrict__ ebuf,
                                                  const int* __restrict__ rowptr,
                                                  int* __restrict__ csrc, int N) {
    __shared__ int lrow[256], lcur[256];
    int b = blockIdx.x;
    int d0 = b << BKT_SHIFT;
    int nd = min(256, N - d0);
    int t = threadIdx.x;
    if (t < nd) lrow[t] = rowptr[d0 + t];
    lcur[t] = 0;
    __syncthreads();
    int beg = rowptr[d0];
    int end = rowptr[min(d0 + 256, N)];
    for (int i = beg + t; i < end; i += 256) {
        int2 e = ebuf[i];
        int ld = e.y - d0;
        int p = lrow[ld] + atomicAdd(&lcur[ld], 1);
        csrc[p] = e.x;
    }
}

// ---------------- GEMM + attention logits (W in VGPRs, float4 x loads) ----------------
template <int K>
__global__ __launch_bounds__(256, 2) void gemm32(
    const float* __restrict__ X, const float* __restrict__ W,
    const float* __restrict__ AL, const float* __restrict__ AR,
    __half* __restrict__ feat16, float* __restrict__ el, float* __restrict__ er, int N) {
    int wave = threadIdx.x >> 6, lane = threadIdx.x & 63;
    float w[K];
#pragma unroll
    for (int k = 0; k < K; k++) w[k] = W[k * 64 + lane];
    float alv = AL[lane], arv = AR[lane];
    for (int n0 = blockIdx.x * 4 + wave; n0 < N; n0 += gridDim.x * 4) {
        int n = rfl(n0);
        const float4* __restrict__ x4 = (const float4*)(X + (size_t)n * K);
        float acc = 0.f;
#pragma unroll
        for (int k4 = 0; k4 < K / 4; k4++) {
            float4 xv = x4[k4];
            acc = fmaf(xv.x, w[4 * k4 + 0], acc);
            acc = fmaf(xv.y, w[4 * k4 + 1], acc);
            acc = fmaf(xv.z, w[4 * k4 + 2], acc);
            acc = fmaf(xv.w, w[4 * k4 + 3], acc);
        }
        feat16[(size_t)n * 64 + lane] = __float2half(acc);
        float vl = acc * alv, vr = acc * arv;
#pragma unroll
        for (int m = 1; m < 32; m <<= 1) {
            vl += __shfl_xor(vl, m, 64);
            vr += __shfl_xor(vr, m, 64);
        }
        if ((lane & 31) == 0) {
            int h = lane >> 5;
            el[n * 2 + h] = vl;
            er[n * 2 + h] = vr;
        }
    }
}

__global__ __launch_bounds__(256, 2) void gemm64(
    const float* __restrict__ X, const float* __restrict__ W,
    const float* __restrict__ AL, const float* __restrict__ AR,
    __half2* __restrict__ feat2, float* __restrict__ el, float* __restrict__ er, int N) {
    int wave = threadIdx.x >> 6, d = threadIdx.x & 63;
    float w0[64], w1[64];
#pragma unroll
    for (int k = 0; k < 64; k++) {
        w0[k] = W[k * 128 + d];
        w1[k] = W[k * 128 + 64 + d];
    }
    float al0 = AL[d], al1 = AL[64 + d], ar0 = AR[d], ar1 = AR[64 + d];
    for (int n0 = blockIdx.x * 4 + wave; n0 < N; n0 += gridDim.x * 4) {
        int n = rfl(n0);
        const float4* __restrict__ x4 = (const float4*)(X + (size_t)n * 64);
        float a0 = 0.f, a1 = 0.f;
#pragma unroll
        for (int k4 = 0; k4 < 16; k4++) {
            float4 xv = x4[k4];
            a0 = fmaf(xv.x, w0[4 * k4 + 0], a0); a1 = fmaf(xv.x, w1[4 * k4 + 0], a1);
            a0 = fmaf(xv.y, w0[4 * k4 + 1], a0); a1 = fmaf(xv.y, w1[4 * k4 + 1], a1);
            a0 = fmaf(xv.z, w0[4 * k4 + 2], a0); a1 = fmaf(xv.z, w1[4 * k4 + 2], a1);
            a0 = fmaf(xv.w, w0[4 * k4 + 3], a0); a1 = fmaf(xv.w, w1[4 * k4 + 3], a1);
        }
        feat2[(size_t)n * 64 + d] = __floats2half2_rn(a0, a1);
        float l0 = a0 * al0, r0 = a0 * ar0;
        float l1 = a1 * al1, r1 = a1 * ar1;
#pragma unroll
        for (int m = 1; m < 64; m <<= 1) {
            l0 += __shfl_xor(l0, m, 64);
            r0 += __shfl_xor(r0, m, 64);
            l1 += __shfl_xor(l1, m, 64);
            r1 += __shfl_xor(r1, m, 64);
        }
        if (d == 0) {
            el[n * 2 + 0] = l0; el[n * 2 + 1] = l1;
            er[n * 2 + 0] = r0; er[n * 2 + 1] = r1;
        }
    }
}

// ---------------- Aggregation (fused edge weights, unroll x8) ----------------
// NOTE: every __shfl executes with FULL exec mask; head-select AFTER broadcast.
template <bool RELU>
__global__ __launch_bounds__(256) void aggregate32(
    const int* __restrict__ rowptr, const int* __restrict__ csrc,
    const float2* __restrict__ el2, const float2* __restrict__ er2,
    const __half* __restrict__ feat16, const float* __restrict__ b,
    float* __restrict__ out, int N) {
    int wave = threadIdx.x >> 6, lane = threadIdx.x & 63, h = lane >> 5;
    int n = rfl(blockIdx.x * 4 + wave);
    if (n >= N) return;
    float bl = b[lane];
    int beg = rfl(rowptr[n]), end = rfl(rowptr[n + 1]);
    float2 rr = er2[n];
    float s = 0.f, acc = 0.f;
    for (int base = beg; base < end; base += 64) {
        int idx = base + lane;
        int sv = 0; float wxv = 0.f, wyv = 0.f;
        if (idx < end) {
            sv = csrc[idx];
            float2 l = el2[sv];
            float t0 = l.x + rr.x; t0 = t0 > 0.f ? t0 : NEG_SLOPE * t0;
            float t1 = l.y + rr.y; t1 = t1 > 0.f ? t1 : NEG_SLOPE * t1;
            wxv = __expf(t0); wyv = __expf(t1);
        }
        int cnt = min(64, end - base);
        int j = 0;
        for (; j + 7 < cnt; j += 8) {
            float fv[8], wv[8];
#pragma unroll
            for (int u = 0; u < 8; u++) {
                int su = __shfl(sv, j + u, 64);
                float wxu = __shfl(wxv, j + u, 64);
                float wyu = __shfl(wyv, j + u, 64);
                wv[u] = h ? wyu : wxu;
                fv[u] = __half2float(feat16[(size_t)su * 64 + lane]);
            }
#pragma unroll
            for (int u = 0; u < 8; u++) {
                s += wv[u];
                acc = fmaf(wv[u], fv[u], acc);
            }
        }
        for (; j < cnt; j++) {
            int s0 = __shfl(sv, j, 64);
            float wx0 = __shfl(wxv, j, 64), wy0 = __shfl(wyv, j, 64);
            float w0 = h ? wy0 : wx0;
            float f0 = __half2float(feat16[(size_t)s0 * 64 + lane]);
            s += w0;
            acc = fmaf(w0, f0, acc);
        }
    }
    float v = (s > 0.f) ? acc / s : 0.f;
    v += bl;
    if (RELU) v = fmaxf(v, 0.f);
    out[(size_t)n * 64 + lane] = v;
}

__global__ __launch_bounds__(256) void aggregate64_mean(
    const int* __restrict__ rowptr, const int* __restrict__ csrc,
    const float2* __restrict__ el2, const float2* __restrict__ er2,
    const __half2* __restrict__ feat2, const float* __restrict__ b,
    float* __restrict__ out, int N) {
    int wave = threadIdx.x >> 6, lane = threadIdx.x & 63;
    int n = rfl(blockIdx.x * 4 + wave);
    if (n >= N) return;
    float b0 = b[lane], b1 = b[64 + lane];
    int beg = rfl(rowptr[n]), end = rfl(rowptr[n + 1]);
    float2 rr = er2[n];
    float s0 = 0.f, s1 = 0.f, a0 = 0.f, a1 = 0.f;
    for (int base = beg; base < end; base += 64) {
        int idx = base + lane;
        int sv = 0; float wxv = 0.f, wyv = 0.f;
        if (idx < end) {
            sv = csrc[idx];
            float2 l = el2[sv];
            float t0 = l.x + rr.x; t0 = t0 > 0.f ? t0 : NEG_SLOPE * t0;
            float t1 = l.y + rr.y; t1 = t1 > 0.f ? t1 : NEG_SLOPE * t1;
            wxv = __expf(t0); wyv = __expf(t1);
        }
        int cnt = min(64, end - base);
        int j = 0;
        for (; j + 7 < cnt; j += 8) {
            float2 fv[8]; float wxs[8], wys[8];
#pragma unroll
            for (int u = 0; u < 8; u++) {
                int eu = __shfl(sv, j + u, 64);
                wxs[u] = __shfl(wxv, j + u, 64);
                wys[u] = __shfl(wyv, j + u, 64);
                fv[u] = __half22float2(feat2[(size_t)eu * 64 + lane]);
            }
#pragma unroll
            for (int u = 0; u < 8; u++) {
                s0 += wxs[u]; s1 += wys[u];
                a0 = fmaf(wxs[u], fv[u].x, a0);
                a1 = fmaf(wys[u], fv[u].y, a1);
            }
        }
        for (; j < cnt; j++) {
            int e0 = __shfl(sv, j, 64);
            float wx0 = __shfl(wxv, j, 64), wy0 = __shfl(wyv, j, 64);
            float2 f0 = __half22float2(feat2[(size_t)e0 * 64 + lane]);
            s0 += wx0; s1 += wy0;
            a0 = fmaf(wx0, f0.x, a0); a1 = fmaf(wy0, f0.y, a1);
        }
    }
    float v0 = (s0 > 0.f) ? a0 / s0 : 0.f;
    float v1 = (s1 > 0.f) ? a1 / s1 : 0.f;
    out[(size_t)n * 64 + lane] = 0.5f * ((v0 + b0) + (v1 + b1));
}

// ---------------- launcher ----------------

extern "C" void kernel_launch(void* const* d_in, const int* in_sizes, int n_in,
                              void* d_out, int out_size, void* d_ws, size_t ws_size,
                              hipStream_t stream) {
    const float* x   = (const float*)d_in[0];
    const int*   src = (const int*)d_in[1];
    const int*   dst = (const int*)d_in[2];
    const float* W0  = (const float*)d_in[3];
    const float* al0 = (const float*)d_in[4];
    const float* ar0 = (const float*)d_in[5];
    const float* b0  = (const float*)d_in[6];
    const float* W1  = (const float*)d_in[7];
    const float* al1 = (const float*)d_in[8];
    const float* ar1 = (const float*)d_in[9];
    const float* b1  = (const float*)d_in[10];
    const float* W2  = (const float*)d_in[11];
    const float* al2 = (const float*)d_in[12];
    const float* ar2 = (const float*)d_in[13];
    const float* b2  = (const float*)d_in[14];
    float* out = (float*)d_out;

    const int N = NNODES;
    const int E = in_sizes[1];

    char* p = (char*)d_ws;
    auto alloc = [&](size_t bytes) {
        void* r = (void*)p;
        p += (bytes + 255) & ~(size_t)255;
        return r;
    };
    int*    deg      = (int*)alloc((size_t)N * 4);
    int*    rowptr   = (int*)alloc((size_t)(N + 1) * 4);
    int*    blocksum = (int*)alloc(256 * 4);
    int*    bcursor  = (int*)alloc((size_t)NBKT * 16 * 4);   // 64 B padded cursors
    int2*   ebuf     = (int2*)alloc((size_t)E * 8);
    int*    csrc     = (int*)alloc((size_t)E * 4);
    float*  el       = (float*)alloc((size_t)N * 2 * 4);
    float*  er       = (float*)alloc((size_t)N * 2 * 4);
    void*   featbuf  = alloc((size_t)N * 64 * 4);
    float*  hbuf     = (float*)alloc((size_t)N * 64 * 4);
    __half*  feat16 = (__half*)featbuf;
    __half2* feat2  = (__half2*)featbuf;
    float2* el2 = (float2*)el;
    float2* er2 = (float2*)er;

    // CSR build (graph is layer-invariant)
    hipMemsetAsync(deg, 0, (size_t)N * 4, stream);
    int eb = (E + 255) / 256;
    int nb256 = (N + 255) / 256;
    count_deg<<<eb, 256, 0, stream>>>(dst, deg, E);
    scan_partial<<<nb256, 256, 0, stream>>>(deg, blocksum, N);
    scan_blocksums<<<1, 256, 0, stream>>>(blocksum, nb256);
    scan_final<<<nb256, 256, 0, stream>>>(deg, blocksum, rowptr, N, E);
    init_bcursor<<<1, 256, 0, stream>>>(rowptr, bcursor);
    int pb = (E + 1024 * PEPT - 1) / (1024 * PEPT);
    partition_edges<<<pb, 1024, 0, stream>>>(src, dst, bcursor, ebuf, E);
    local_sort<<<NBKT, 256, 0, stream>>>(ebuf, rowptr, csrc, N);

    int nb4 = (N + 3) / 4;        // one wave per node
    int gemmGrid = 2048;          // grid-stride

    // layer 0: IN=128 -> H2xD32
    gemm32<128><<<gemmGrid, 256, 0, stream>>>(x, W0, al0, ar0, feat16, el, er, N);
    aggregate32<true><<<nb4, 256, 0, stream>>>(rowptr, csrc, el2, er2, feat16, b0, hbuf, N);

    // layer 1: 64 -> H2xD32
    gemm32<64><<<gemmGrid, 256, 0, stream>>>(hbuf, W1, al1, ar1, feat16, el, er, N);
    aggregate32<true><<<nb4, 256, 0, stream>>>(rowptr, csrc, el2, er2, feat16, b1, hbuf, N);

    // layer 2: 64 -> H2xD64, mean over heads
    gemm64<<<gemmGrid, 256, 0, stream>>>(hbuf, W2, al2, ar2, feat2, el, er, N);
    aggregate64_mean<<<nb4, 256, 0, stream>>>(rowptr, csrc, el2, er2, feat2, b2, out, N);
}

// Round 9
// 303.651 us; speedup vs baseline: 1.3817x; 1.1284x over previous
//
#include <hip/hip_runtime.h>
#include <hip/hip_bf16.h>
#include <hip/hip_fp16.h>

#define NNODES 50000
#define NEG_SLOPE 0.2f
#define BKT_SHIFT 8
#define NBKT ((NNODES + 255) >> 8)   // 196 buckets of 256 dsts
#define PEPT 8                        // partition: edges per thread

typedef _Float16 half8 __attribute__((ext_vector_type(8)));
typedef _Float16 half4_t __attribute__((ext_vector_type(4)));
typedef float v4f __attribute__((ext_vector_type(4)));

__device__ __forceinline__ int rfl(int v) { return __builtin_amdgcn_readfirstlane(v); }

// ---------------- CSR build (unchanged from R8) ----------------

__global__ void count_deg(const int* __restrict__ dst, int* __restrict__ deg, int E) {
    int i = blockIdx.x * blockDim.x + threadIdx.x;
    if (i < E) atomicAdd(&deg[dst[i]], 1);
}

__global__ void scan_partial(const int* __restrict__ deg, int* __restrict__ blocksum, int N) {
    int i = blockIdx.x * 256 + threadIdx.x;
    int v = (i < N) ? deg[i] : 0;
#pragma unroll
    for (int m = 1; m < 64; m <<= 1) v += __shfl_xor(v, m, 64);
    __shared__ int ws[4];
    if ((threadIdx.x & 63) == 0) ws[threadIdx.x >> 6] = v;
    __syncthreads();
    if (threadIdx.x == 0) blocksum[blockIdx.x] = ws[0] + ws[1] + ws[2] + ws[3];
}

__global__ void scan_blocksums(int* __restrict__ blocksum, int nb) {
    __shared__ int buf[256];
    int t = threadIdx.x;
    int v = (t < nb) ? blocksum[t] : 0;
    buf[t] = v;
    __syncthreads();
    for (int off = 1; off < 256; off <<= 1) {
        int x = (t >= off) ? buf[t - off] : 0;
        __syncthreads();
        buf[t] += x;
        __syncthreads();
    }
    if (t < nb) blocksum[t] = buf[t] - v;  // exclusive
}

__global__ void scan_final(const int* __restrict__ deg, const int* __restrict__ blocksum,
                           int* __restrict__ rowptr, int N, int E) {
    int i = blockIdx.x * 256 + threadIdx.x;
    int lane = threadIdx.x & 63;
    int v = (i < N) ? deg[i] : 0;
    int x = v;
#pragma unroll
    for (int m = 1; m < 64; m <<= 1) {
        int y = __shfl_up(x, m, 64);
        if (lane >= m) x += y;
    }
    __shared__ int ws[4];
    if (lane == 63) ws[threadIdx.x >> 6] = x;
    __syncthreads();
    int w = threadIdx.x >> 6;
    int waveoff = 0;
#pragma unroll
    for (int k = 0; k < 4; k++) if (k < w) waveoff += ws[k];
    int excl = blocksum[blockIdx.x] + waveoff + x - v;
    if (i < N) rowptr[i] = excl;
    if (i == N - 1) rowptr[N] = E;
}

__global__ void init_bcursor(const int* __restrict__ rowptr, int* __restrict__ bcursor) {
    int t = blockIdx.x * 256 + threadIdx.x;
    if (t < NBKT) bcursor[t * 16] = rowptr[t << BKT_SHIFT];
}

__global__ __launch_bounds__(1024) void partition_edges(
    const int* __restrict__ src, const int* __restrict__ dst,
    int* __restrict__ bcursor, int2* __restrict__ ebuf, int E) {
    __shared__ int hist[NBKT];
    __shared__ int gbase[NBKT];
    int t = threadIdx.x;
    for (int i = t; i < NBKT; i += 1024) hist[i] = 0;
    __syncthreads();
    int base = blockIdx.x * 1024 * PEPT;
    int sreg[PEPT], dreg[PEPT], rreg[PEPT], breg[PEPT];
#pragma unroll
    for (int k = 0; k < PEPT; k++) {
        int i = base + k * 1024 + t;
        if (i < E) {
            sreg[k] = src[i];
            dreg[k] = dst[i];
            breg[k] = dreg[k] >> BKT_SHIFT;
            rreg[k] = atomicAdd(&hist[breg[k]], 1);
        } else {
            breg[k] = -1;
        }
    }
    __syncthreads();
    for (int i = t; i < NBKT; i += 1024)
        if (hist[i]) gbase[i] = atomicAdd(&bcursor[i * 16], hist[i]);
    __syncthreads();
#pragma unroll
    for (int k = 0; k < PEPT; k++) {
        if (breg[k] >= 0)
            ebuf[(size_t)(gbase[breg[k]] + rreg[k])] = make_int2(sreg[k], dreg[k]);
    }
}

__global__ __launch_bounds__(256) void local_sort(const int2* __restrict__ ebuf,
                                                  const int* __restrict__ rowptr,
                                                  int* __restrict__ csrc, int N) {
    __shared__ int lrow[256], lcur[256];
    int b = blockIdx.x;
    int d0 = b << BKT_SHIFT;
    int nd = min(256, N - d0);
    int t = threadIdx.x;
    if (t < nd) lrow[t] = rowptr[d0 + t];
    lcur[t] = 0;
    __syncthreads();
    int beg = rowptr[d0];
    int end = rowptr[min(d0 + 256, N)];
    for (int i = beg + t; i < end; i += 256) {
        int2 e = ebuf[i];
        int ld = e.y - d0;
        int p = lrow[ld] + atomicAdd(&lcur[ld], 1);
        csrc[p] = e.x;
    }
}

// ---------------- fp16-split conversion + W packing ----------------

// split fp32 -> hi fp16 + residual fp16 (exact to ~2^-22)
__global__ void split_fp16(const float* __restrict__ in, _Float16* __restrict__ hi,
                           _Float16* __restrict__ lo, int total4) {
    int i = blockIdx.x * 256 + threadIdx.x;
    if (i >= total4) return;
    float4 v = ((const float4*)in)[i];
    half4_t h, l;
    h[0] = (_Float16)v.x; l[0] = (_Float16)(v.x - (float)h[0]);
    h[1] = (_Float16)v.y; l[1] = (_Float16)(v.y - (float)h[1]);
    h[2] = (_Float16)v.z; l[2] = (_Float16)(v.z - (float)h[2]);
    h[3] = (_Float16)v.w; l[3] = (_Float16)(v.w - (float)h[3]);
    ((half4_t*)hi)[i] = h;
    ((half4_t*)lo)[i] = l;
}

// pack W[K][C] fp32 into MFMA B-fragment order:
// Wp[((t*KC+kc)*64+l)*8 + j] = W[kc*32 + (l>>4)*8 + j][t*16 + (l&15)]
__global__ void pack_w(const float* __restrict__ W, _Float16* __restrict__ Wp,
                       int K, int C) {
    int KC = K / 32;
    int tid = blockIdx.x * 256 + threadIdx.x;
    int total = (C / 16) * KC * 64;
    if (tid >= total) return;
    int l = tid & 63;
    int kc = (tid >> 6) % KC;
    int t = tid / (KC * 64);
    int cc = l & 15, q = l >> 4;
    half8 b;
#pragma unroll
    for (int j = 0; j < 8; j++)
        b[j] = (_Float16)W[(size_t)(kc * 32 + q * 8 + j) * C + t * 16 + cc];
    *(half8*)(Wp + (size_t)tid * 8) = b;
}

// ---------------- MFMA GEMM + attention logits ----------------
// D = (Ahi+Alo) @ W. One wave per 16-row m-tile, all C columns.
// Verified gfx950 16x16x32 layouts: A[m=lane&15][k=(lane>>4)*8+j],
// B[k=(lane>>4)*8+j][n=lane&15], C/D: col=lane&15, row=(lane>>4)*4+reg.
template <int K, int C, bool INTERLEAVE>
__global__ __launch_bounds__(256) void gemm_mfma(
    const _Float16* __restrict__ Ahi, const _Float16* __restrict__ Alo,
    const _Float16* __restrict__ Wp,
    const float* __restrict__ AL, const float* __restrict__ AR,
    void* __restrict__ featout, float2* __restrict__ el2, float2* __restrict__ er2,
    int N) {
    constexpr int KC = K / 32;
    constexpr int NT = C / 16;
    int wave = threadIdx.x >> 6, lane = threadIdx.x & 63;
    int mtile = blockIdx.x * 4 + wave;
    if (mtile * 16 >= N) return;
    int m0 = mtile * 16;
    int c = lane & 15, q = lane >> 4;

    v4f acc[NT];
#pragma unroll
    for (int t = 0; t < NT; t++) acc[t] = (v4f){0.f, 0.f, 0.f, 0.f};

    const size_t arow = (size_t)(m0 + c) * K + q * 8;
#pragma unroll
    for (int kc = 0; kc < KC; kc++) {
        half8 ah = *(const half8*)(Ahi + arow + kc * 32);
        half8 av = *(const half8*)(Alo + arow + kc * 32);
#pragma unroll
        for (int t = 0; t < NT; t++) {
            half8 b = *(const half8*)(Wp + ((size_t)(t * KC + kc) * 64 + lane) * 8);
            acc[t] = __builtin_amdgcn_mfma_f32_16x16x32_f16(ah, b, acc[t], 0, 0, 0);
            acc[t] = __builtin_amdgcn_mfma_f32_16x16x32_f16(av, b, acc[t], 0, 0, 0);
        }
    }

    // feat store
    if (!INTERLEAVE) {
        _Float16* f16 = (_Float16*)featout;
#pragma unroll
        for (int t = 0; t < NT; t++)
#pragma unroll
            for (int r = 0; r < 4; r++) {
                int row = m0 + q * 4 + r;
                f16[(size_t)row * C + t * 16 + c] = (_Float16)acc[t][r];
            }
    } else {
        // C=128: pair head0 (tiles 0..NT/2-1) with head1 (tiles NT/2..) as half2
        __half2* f2 = (__half2*)featout;
#pragma unroll
        for (int t = 0; t < NT / 2; t++)
#pragma unroll
            for (int r = 0; r < 4; r++) {
                int row = m0 + q * 4 + r;
                f2[(size_t)row * (C / 2) + t * 16 + c] =
                    __floats2half2_rn(acc[t][r], acc[t + NT / 2][r]);
            }
    }

    // el/er from fp32 accs: head0 = tiles [0,NT/2), head1 = rest
    float alv[NT], arv[NT];
#pragma unroll
    for (int t = 0; t < NT; t++) { alv[t] = AL[t * 16 + c]; arv[t] = AR[t * 16 + c]; }
#pragma unroll
    for (int r = 0; r < 4; r++) {
        float l0 = 0.f, l1 = 0.f, r0 = 0.f, r1 = 0.f;
#pragma unroll
        for (int t = 0; t < NT; t++) {
            float v = acc[t][r];
            if (t < NT / 2) { l0 = fmaf(v, alv[t], l0); r0 = fmaf(v, arv[t], r0); }
            else            { l1 = fmaf(v, alv[t], l1); r1 = fmaf(v, arv[t], r1); }
        }
#pragma unroll
        for (int m = 1; m < 16; m <<= 1) {
            l0 += __shfl_xor(l0, m, 64);
            l1 += __shfl_xor(l1, m, 64);
            r0 += __shfl_xor(r0, m, 64);
            r1 += __shfl_xor(r1, m, 64);
        }
        if (c == 0) {
            int row = m0 + q * 4 + r;
            el2[row] = make_float2(l0, l1);
            er2[row] = make_float2(r0, r1);
        }
    }
}

// ---------------- Aggregation (fused edge weights, unroll x8) ----------------
// NOTE: every __shfl executes with FULL exec mask; head-select AFTER broadcast.
// Output: bias+ReLU, then split fp32 -> hi/lo fp16 (next layer's MFMA input).
__global__ __launch_bounds__(256) void aggregate32(
    const int* __restrict__ rowptr, const int* __restrict__ csrc,
    const float2* __restrict__ el2, const float2* __restrict__ er2,
    const _Float16* __restrict__ feat16, const float* __restrict__ b,
    _Float16* __restrict__ ahi, _Float16* __restrict__ alo, int N) {
    int wave = threadIdx.x >> 6, lane = threadIdx.x & 63, h = lane >> 5;
    int n = rfl(blockIdx.x * 4 + wave);
    if (n >= N) return;
    float bl = b[lane];
    int beg = rfl(rowptr[n]), end = rfl(rowptr[n + 1]);
    float2 rr = er2[n];
    float s = 0.f, acc = 0.f;
    for (int base = beg; base < end; base += 64) {
        int idx = base + lane;
        int sv = 0; float wxv = 0.f, wyv = 0.f;
        if (idx < end) {
            sv = csrc[idx];
            float2 l = el2[sv];
            float t0 = l.x + rr.x; t0 = t0 > 0.f ? t0 : NEG_SLOPE * t0;
            float t1 = l.y + rr.y; t1 = t1 > 0.f ? t1 : NEG_SLOPE * t1;
            wxv = __expf(t0); wyv = __expf(t1);
        }
        int cnt = min(64, end - base);
        int j = 0;
        for (; j + 7 < cnt; j += 8) {
            float fv[8], wv[8];
#pragma unroll
            for (int u = 0; u < 8; u++) {
                int su = __shfl(sv, j + u, 64);
                float wxu = __shfl(wxv, j + u, 64);
                float wyu = __shfl(wyv, j + u, 64);
                wv[u] = h ? wyu : wxu;
                fv[u] = (float)feat16[(size_t)su * 64 + lane];
            }
#pragma unroll
            for (int u = 0; u < 8; u++) {
                s += wv[u];
                acc = fmaf(wv[u], fv[u], acc);
            }
        }
        for (; j < cnt; j++) {
            int s0 = __shfl(sv, j, 64);
            float wx0 = __shfl(wxv, j, 64), wy0 = __shfl(wyv, j, 64);
            float w0 = h ? wy0 : wx0;
            float f0 = (float)feat16[(size_t)s0 * 64 + lane];
            s += w0;
            acc = fmaf(w0, f0, acc);
        }
    }
    float v = (s > 0.f) ? acc / s : 0.f;
    v = fmaxf(v + bl, 0.f);
    _Float16 hv = (_Float16)v;
    ahi[(size_t)n * 64 + lane] = hv;
    alo[(size_t)n * 64 + lane] = (_Float16)(v - (float)hv);
}

__global__ __launch_bounds__(256) void aggregate64_mean(
    const int* __restrict__ rowptr, const int* __restrict__ csrc,
    const float2* __restrict__ el2, const float2* __restrict__ er2,
    const __half2* __restrict__ feat2, const float* __restrict__ b,
    float* __restrict__ out, int N) {
    int wave = threadIdx.x >> 6, lane = threadIdx.x & 63;
    int n = rfl(blockIdx.x * 4 + wave);
    if (n >= N) return;
    float b0 = b[lane], b1 = b[64 + lane];
    int beg = rfl(rowptr[n]), end = rfl(rowptr[n + 1]);
    float2 rr = er2[n];
    float s0 = 0.f, s1 = 0.f, a0 = 0.f, a1 = 0.f;
    for (int base = beg; base < end; base += 64) {
        int idx = base + lane;
        int sv = 0; float wxv = 0.f, wyv = 0.f;
        if (idx < end) {
            sv = csrc[idx];
            float2 l = el2[sv];
            float t0 = l.x + rr.x; t0 = t0 > 0.f ? t0 : NEG_SLOPE * t0;
            float t1 = l.y + rr.y; t1 = t1 > 0.f ? t1 : NEG_SLOPE * t1;
            wxv = __expf(t0); wyv = __expf(t1);
        }
        int cnt = min(64, end - base);
        int j = 0;
        for (; j + 7 < cnt; j += 8) {
            float2 fv[8]; float wxs[8], wys[8];
#pragma unroll
            for (int u = 0; u < 8; u++) {
                int eu = __shfl(sv, j + u, 64);
                wxs[u] = __shfl(wxv, j + u, 64);
                wys[u] = __shfl(wyv, j + u, 64);
                fv[u] = __half22float2(feat2[(size_t)eu * 64 + lane]);
            }
#pragma unroll
            for (int u = 0; u < 8; u++) {
                s0 += wxs[u]; s1 += wys[u];
                a0 = fmaf(wxs[u], fv[u].x, a0);
                a1 = fmaf(wys[u], fv[u].y, a1);
            }
        }
        for (; j < cnt; j++) {
            int e0 = __shfl(sv, j, 64);
            float wx0 = __shfl(wxv, j, 64), wy0 = __shfl(wyv, j, 64);
            float2 f0 = __half22float2(feat2[(size_t)e0 * 64 + lane]);
            s0 += wx0; s1 += wy0;
            a0 = fmaf(wx0, f0.x, a0); a1 = fmaf(wy0, f0.y, a1);
        }
    }
    float v0 = (s0 > 0.f) ? a0 / s0 : 0.f;
    float v1 = (s1 > 0.f) ? a1 / s1 : 0.f;
    out[(size_t)n * 64 + lane] = 0.5f * ((v0 + b0) + (v1 + b1));
}

// ---------------- launcher ----------------

extern "C" void kernel_launch(void* const* d_in, const int* in_sizes, int n_in,
                              void* d_out, int out_size, void* d_ws, size_t ws_size,
                              hipStream_t stream) {
    const float* x   = (const float*)d_in[0];
    const int*   src = (const int*)d_in[1];
    const int*   dst = (const int*)d_in[2];
    const float* W0  = (const float*)d_in[3];
    const float* al0 = (const float*)d_in[4];
    const float* ar0 = (const float*)d_in[5];
    const float* b0  = (const float*)d_in[6];
    const float* W1  = (const float*)d_in[7];
    const float* al1 = (const float*)d_in[8];
    const float* ar1 = (const float*)d_in[9];
    const float* b1  = (const float*)d_in[10];
    const float* W2  = (const float*)d_in[11];
    const float* al2 = (const float*)d_in[12];
    const float* ar2 = (const float*)d_in[13];
    const float* b2  = (const float*)d_in[14];
    float* out = (float*)d_out;

    const int N = NNODES;
    const int E = in_sizes[1];

    char* p = (char*)d_ws;
    auto alloc = [&](size_t bytes) {
        void* r = (void*)p;
        p += (bytes + 255) & ~(size_t)255;
        return r;
    };
    int*    deg      = (int*)alloc((size_t)N * 4);
    int*    rowptr   = (int*)alloc((size_t)(N + 1) * 4);
    int*    blocksum = (int*)alloc(256 * 4);
    int*    bcursor  = (int*)alloc((size_t)NBKT * 16 * 4);
    int2*   ebuf     = (int2*)alloc((size_t)E * 8);
    int*    csrc     = (int*)alloc((size_t)E * 4);
    float2* el2      = (float2*)alloc((size_t)N * 8);
    float2* er2      = (float2*)alloc((size_t)N * 8);
    _Float16* ahi    = (_Float16*)alloc((size_t)N * 128 * 2);
    _Float16* alo    = (_Float16*)alloc((size_t)N * 128 * 2);
    void*   featbuf  = alloc((size_t)N * 64 * 4);   // fp16[N][64] or half2[N][64]
    _Float16* Wp0    = (_Float16*)alloc(4 * 4 * 64 * 8 * 2);
    _Float16* Wp1    = (_Float16*)alloc(4 * 2 * 64 * 8 * 2);
    _Float16* Wp2    = (_Float16*)alloc(8 * 2 * 64 * 8 * 2);
    _Float16* feat16 = (_Float16*)featbuf;
    __half2*  feat2  = (__half2*)featbuf;

    // CSR build (graph is layer-invariant)
    hipMemsetAsync(deg, 0, (size_t)N * 4, stream);
    int eb = (E + 255) / 256;
    int nb256 = (N + 255) / 256;
    count_deg<<<eb, 256, 0, stream>>>(dst, deg, E);
    scan_partial<<<nb256, 256, 0, stream>>>(deg, blocksum, N);
    scan_blocksums<<<1, 256, 0, stream>>>(blocksum, nb256);
    scan_final<<<nb256, 256, 0, stream>>>(deg, blocksum, rowptr, N, E);
    init_bcursor<<<1, 256, 0, stream>>>(rowptr, bcursor);
    int pb = (E + 1024 * PEPT - 1) / (1024 * PEPT);
    partition_edges<<<pb, 1024, 0, stream>>>(src, dst, bcursor, ebuf, E);
    local_sort<<<NBKT, 256, 0, stream>>>(ebuf, rowptr, csrc, N);

    // weight packing + input split
    pack_w<<<4, 256, 0, stream>>>(W0, Wp0, 128, 64);
    pack_w<<<2, 256, 0, stream>>>(W1, Wp1, 64, 64);
    pack_w<<<4, 256, 0, stream>>>(W2, Wp2, 64, 128);
    int t4 = N * 128 / 4;
    split_fp16<<<(t4 + 255) / 256, 256, 0, stream>>>(x, ahi, alo, t4);

    int nb4 = (N + 3) / 4;               // aggregation: one wave per node
    int gb = (N / 16 + 3) / 4;           // gemm: one wave per 16-row tile

    // layer 0: IN=128 -> H2xD32
    gemm_mfma<128, 64, false><<<gb, 256, 0, stream>>>(ahi, alo, Wp0, al0, ar0, featbuf, el2, er2, N);
    aggregate32<<<nb4, 256, 0, stream>>>(rowptr, csrc, el2, er2, feat16, b0, ahi, alo, N);

    // layer 1: 64 -> H2xD32
    gemm_mfma<64, 64, false><<<gb, 256, 0, stream>>>(ahi, alo, Wp1, al1, ar1, featbuf, el2, er2, N);
    aggregate32<<<nb4, 256, 0, stream>>>(rowptr, csrc, el2, er2, feat16, b1, ahi, alo, N);

    // layer 2: 64 -> H2xD64, mean over heads (interleaved half2 feat)
    gemm_mfma<64, 128, true><<<gb, 256, 0, stream>>>(ahi, alo, Wp2, al2, ar2, featbuf, el2, er2, N);
    aggregate64_mean<<<nb4, 256, 0, stream>>>(rowptr, csrc, el2, er2, feat2, b2, out, N);
}

// Round 10
// 265.991 us; speedup vs baseline: 1.5774x; 1.1416x over previous
//
#include <hip/hip_runtime.h>
#include <hip/hip_bf16.h>
#include <hip/hip_fp16.h>

#define NNODES 50000
#define NEG_SLOPE 0.2f
#define BKT_SHIFT 8
#define NBKT ((NNODES + 255) >> 8)   // 196 buckets of 256 dsts
#define PEPT 8                        // partition: edges per thread

typedef _Float16 half8 __attribute__((ext_vector_type(8)));
typedef _Float16 half4_t __attribute__((ext_vector_type(4)));
typedef float v4f __attribute__((ext_vector_type(4)));

__device__ __forceinline__ int rfl(int v) { return __builtin_amdgcn_readfirstlane(v); }

// ---------------- CSR build (bucket-only histogram; rowptr built in local_sort) ----

// per-bucket histogram only (LDS privatized; 196 global atomics per block)
__global__ void bucket_hist(const int* __restrict__ dst, int* __restrict__ bhist, int E) {
    __shared__ int lh[NBKT];
    for (int i = threadIdx.x; i < NBKT; i += 256) lh[i] = 0;
    __syncthreads();
    for (int i = blockIdx.x * 256 + threadIdx.x; i < E; i += gridDim.x * 256)
        atomicAdd(&lh[dst[i] >> BKT_SHIFT], 1);
    __syncthreads();
    for (int i = threadIdx.x; i < NBKT; i += 256)
        if (lh[i]) atomicAdd(&bhist[i], lh[i]);
}

// exclusive scan of 196 bucket counts -> bbase; init 64B-padded cursors
__global__ void scan_buckets(const int* __restrict__ bhist, int* __restrict__ bbase,
                             int* __restrict__ bcursor) {
    __shared__ int buf[256];
    int t = threadIdx.x;
    int v = (t < NBKT) ? bhist[t] : 0;
    buf[t] = v;
    __syncthreads();
    for (int off = 1; off < 256; off <<= 1) {
        int x = (t >= off) ? buf[t - off] : 0;
        __syncthreads();
        buf[t] += x;
        __syncthreads();
    }
    if (t < NBKT) { int e = buf[t] - v; bbase[t] = e; bcursor[t * 16] = e; }
}

// Block-privatized partition: LDS histogram gives in-block rank; ONE global
// atomic per (bucket, block) reserves a contiguous run; pass 2 fills it.
__global__ __launch_bounds__(1024) void partition_edges(
    const int* __restrict__ src, const int* __restrict__ dst,
    int* __restrict__ bcursor, int2* __restrict__ ebuf, int E) {
    __shared__ int hist[NBKT];
    __shared__ int gbase[NBKT];
    int t = threadIdx.x;
    for (int i = t; i < NBKT; i += 1024) hist[i] = 0;
    __syncthreads();
    int base = blockIdx.x * 1024 * PEPT;
    int sreg[PEPT], dreg[PEPT], rreg[PEPT], breg[PEPT];
#pragma unroll
    for (int k = 0; k < PEPT; k++) {
        int i = base + k * 1024 + t;
        if (i < E) {
            sreg[k] = src[i];
            dreg[k] = dst[i];
            breg[k] = dreg[k] >> BKT_SHIFT;
            rreg[k] = atomicAdd(&hist[breg[k]], 1);
        } else {
            breg[k] = -1;
        }
    }
    __syncthreads();
    for (int i = t; i < NBKT; i += 1024)
        if (hist[i]) gbase[i] = atomicAdd(&bcursor[i * 16], hist[i]);
    __syncthreads();
#pragma unroll
    for (int k = 0; k < PEPT; k++) {
        if (breg[k] >= 0)
            ebuf[(size_t)(gbase[breg[k]] + rreg[k])] = make_int2(sreg[k], dreg[k]);
    }
}

// one block per bucket: count degrees in LDS, in-block exclusive scan ->
// write this bucket's rowptr slice, then place edges (csrc) by LDS cursors.
__global__ __launch_bounds__(256) void local_sort(const int2* __restrict__ ebuf,
                                                  const int* __restrict__ bbase,
                                                  int* __restrict__ rowptr,
                                                  int* __restrict__ csrc, int N, int E) {
    __shared__ int lcnt[256], lrow[256], ws[4];
    int b = blockIdx.x;
    int d0 = b << BKT_SHIFT;
    int t = threadIdx.x;
    int base = bbase[b];
    int endE = (b + 1 < NBKT) ? bbase[b + 1] : E;
    lcnt[t] = 0;
    __syncthreads();
    for (int i = base + t; i < endE; i += 256)
        atomicAdd(&lcnt[ebuf[i].y - d0], 1);
    __syncthreads();
    // exclusive scan of 256 counts (wave scan + cross-wave offsets)
    int v = lcnt[t];
    int lane = t & 63;
    int x = v;
#pragma unroll
    for (int m = 1; m < 64; m <<= 1) {
        int y = __shfl_up(x, m, 64);
        if (lane >= m) x += y;
    }
    if (lane == 63) ws[t >> 6] = x;
    __syncthreads();
    int w = t >> 6, waveoff = 0;
#pragma unroll
    for (int k = 0; k < 4; k++) if (k < w) waveoff += ws[k];
    int excl = base + waveoff + x - v;   // global rowptr value
    lrow[t] = excl;
    int d = d0 + t;
    if (d < N) rowptr[d] = excl;
    if (d == N) rowptr[N] = excl;        // == E, written by the last bucket
    lcnt[t] = 0;
    __syncthreads();
    for (int i = base + t; i < endE; i += 256) {
        int2 e = ebuf[i];
        int ld = e.y - d0;
        int p = lrow[ld] + atomicAdd(&lcnt[ld], 1);
        csrc[p] = e.x;
    }
}

// ---------------- fp16-split conversion + W packing ----------------

__global__ void split_fp16(const float* __restrict__ in, _Float16* __restrict__ hi,
                           _Float16* __restrict__ lo, int total4) {
    int i = blockIdx.x * 256 + threadIdx.x;
    if (i >= total4) return;
    float4 v = ((const float4*)in)[i];
    half4_t h, l;
    h[0] = (_Float16)v.x; l[0] = (_Float16)(v.x - (float)h[0]);
    h[1] = (_Float16)v.y; l[1] = (_Float16)(v.y - (float)h[1]);
    h[2] = (_Float16)v.z; l[2] = (_Float16)(v.z - (float)h[2]);
    h[3] = (_Float16)v.w; l[3] = (_Float16)(v.w - (float)h[3]);
    ((half4_t*)hi)[i] = h;
    ((half4_t*)lo)[i] = l;
}

// pack W[K][C] fp32 into MFMA B-fragment order (see gemm_mfma layouts)
__device__ __forceinline__ void pack_one(const float* W, _Float16* Wp, int K, int C, int tid) {
    int KC = K / 32;
    int l = tid & 63;
    int kc = (tid >> 6) % KC;
    int t = tid / (KC * 64);
    int cc = l & 15, q = l >> 4;
    half8 b;
#pragma unroll
    for (int j = 0; j < 8; j++)
        b[j] = (_Float16)W[(size_t)(kc * 32 + q * 8 + j) * C + t * 16 + cc];
    *(half8*)(Wp + (size_t)tid * 8) = b;
}

// one launch packs all three weight matrices
__global__ void pack_w3(const float* __restrict__ W0, _Float16* __restrict__ Wp0,
                        const float* __restrict__ W1, _Float16* __restrict__ Wp1,
                        const float* __restrict__ W2, _Float16* __restrict__ Wp2) {
    int tid = blockIdx.x * 256 + threadIdx.x;
    const int t0 = 4 * 4 * 64;   // W0: C/16=4, KC=4
    const int t1 = 4 * 2 * 64;   // W1: C/16=4, KC=2
    const int t2 = 8 * 2 * 64;   // W2: C/16=8, KC=2
    if (tid < t0) pack_one(W0, Wp0, 128, 64, tid);
    else if (tid < t0 + t1) pack_one(W1, Wp1, 64, 64, tid - t0);
    else if (tid < t0 + t1 + t2) pack_one(W2, Wp2, 64, 128, tid - t0 - t1);
}

// ---------------- MFMA GEMM + attention logits ----------------
// D = (Ahi+Alo) @ W. One wave per 16-row m-tile, all C columns.
// gfx950 16x16x32 layouts: A[m=lane&15][k=(lane>>4)*8+j],
// B[k=(lane>>4)*8+j][n=lane&15], C/D: col=lane&15, row=(lane>>4)*4+reg.
template <int K, int C, bool INTERLEAVE>
__global__ __launch_bounds__(256) void gemm_mfma(
    const _Float16* __restrict__ Ahi, const _Float16* __restrict__ Alo,
    const _Float16* __restrict__ Wp,
    const float* __restrict__ AL, const float* __restrict__ AR,
    void* __restrict__ featout, float2* __restrict__ el2, float2* __restrict__ er2,
    int N) {
    constexpr int KC = K / 32;
    constexpr int NT = C / 16;
    int wave = threadIdx.x >> 6, lane = threadIdx.x & 63;
    int mtile = blockIdx.x * 4 + wave;
    if (mtile * 16 >= N) return;
    int m0 = mtile * 16;
    int c = lane & 15, q = lane >> 4;

    v4f acc[NT];
#pragma unroll
    for (int t = 0; t < NT; t++) acc[t] = (v4f){0.f, 0.f, 0.f, 0.f};

    const size_t arow = (size_t)(m0 + c) * K + q * 8;
#pragma unroll
    for (int kc = 0; kc < KC; kc++) {
        half8 ah = *(const half8*)(Ahi + arow + kc * 32);
        half8 av = *(const half8*)(Alo + arow + kc * 32);
#pragma unroll
        for (int t = 0; t < NT; t++) {
            half8 b = *(const half8*)(Wp + ((size_t)(t * KC + kc) * 64 + lane) * 8);
            acc[t] = __builtin_amdgcn_mfma_f32_16x16x32_f16(ah, b, acc[t], 0, 0, 0);
            acc[t] = __builtin_amdgcn_mfma_f32_16x16x32_f16(av, b, acc[t], 0, 0, 0);
        }
    }

    if (!INTERLEAVE) {
        _Float16* f16 = (_Float16*)featout;
#pragma unroll
        for (int t = 0; t < NT; t++)
#pragma unroll
            for (int r = 0; r < 4; r++) {
                int row = m0 + q * 4 + r;
                f16[(size_t)row * C + t * 16 + c] = (_Float16)acc[t][r];
            }
    } else {
        __half2* f2 = (__half2*)featout;
#pragma unroll
        for (int t = 0; t < NT / 2; t++)
#pragma unroll
            for (int r = 0; r < 4; r++) {
                int row = m0 + q * 4 + r;
                f2[(size_t)row * (C / 2) + t * 16 + c] =
                    __floats2half2_rn(acc[t][r], acc[t + NT / 2][r]);
            }
    }

    float alv[NT], arv[NT];
#pragma unroll
    for (int t = 0; t < NT; t++) { alv[t] = AL[t * 16 + c]; arv[t] = AR[t * 16 + c]; }
#pragma unroll
    for (int r = 0; r < 4; r++) {
        float l0 = 0.f, l1 = 0.f, r0 = 0.f, r1 = 0.f;
#pragma unroll
        for (int t = 0; t < NT; t++) {
            float v = acc[t][r];
            if (t < NT / 2) { l0 = fmaf(v, alv[t], l0); r0 = fmaf(v, arv[t], r0); }
            else            { l1 = fmaf(v, alv[t], l1); r1 = fmaf(v, arv[t], r1); }
        }
#pragma unroll
        for (int m = 1; m < 16; m <<= 1) {
            l0 += __shfl_xor(l0, m, 64);
            l1 += __shfl_xor(l1, m, 64);
            r0 += __shfl_xor(r0, m, 64);
            r1 += __shfl_xor(r1, m, 64);
        }
        if (c == 0) {
            int row = m0 + q * 4 + r;
            el2[row] = make_float2(l0, l1);
            er2[row] = make_float2(r0, r1);
        }
    }
}

// ---------------- Aggregation (LDS-staged edge broadcast, unroll x8) ----------------
// Per 64-edge chunk: lanes stage {src, wx, wy} into LDS once; the j-loop does one
// uniform-address ds_read_b128 per edge (broadcast, conflict-free) instead of 3
// ds_bpermutes. Intra-wave LDS RAW is safe: DS ops of one wave process in order.
__global__ __launch_bounds__(256) void aggregate32(
    const int* __restrict__ rowptr, const int* __restrict__ csrc,
    const float2* __restrict__ el2, const float2* __restrict__ er2,
    const _Float16* __restrict__ feat16, const float* __restrict__ b,
    _Float16* __restrict__ ahi, _Float16* __restrict__ alo, int N) {
    __shared__ int4 st[4][64];
    int wave = threadIdx.x >> 6, lane = threadIdx.x & 63, h = lane >> 5;
    int n = rfl(blockIdx.x * 4 + wave);
    if (n >= N) return;
    float bl = b[lane];
    int beg = rfl(rowptr[n]), end = rfl(rowptr[n + 1]);
    float2 rr = er2[n];
    float s = 0.f, acc = 0.f;
    for (int base = beg; base < end; base += 64) {
        int idx = base + lane;
        int sv = 0; float wxv = 0.f, wyv = 0.f;
        if (idx < end) {
            sv = csrc[idx];
            float2 l = el2[sv];
            float t0 = l.x + rr.x; t0 = t0 > 0.f ? t0 : NEG_SLOPE * t0;
            float t1 = l.y + rr.y; t1 = t1 > 0.f ? t1 : NEG_SLOPE * t1;
            wxv = __expf(t0); wyv = __expf(t1);
        }
        st[wave][lane] = make_int4(sv, __float_as_int(wxv), __float_as_int(wyv), 0);
        int cnt = min(64, end - base);
        int j = 0;
        for (; j + 7 < cnt; j += 8) {
            float fv[8], wv[8];
#pragma unroll
            for (int u = 0; u < 8; u++) {
                int4 e = st[wave][j + u];
                wv[u] = h ? __int_as_float(e.z) : __int_as_float(e.y);
                fv[u] = (float)feat16[(size_t)e.x * 64 + lane];
            }
#pragma unroll
            for (int u = 0; u < 8; u++) {
                s += wv[u];
                acc = fmaf(wv[u], fv[u], acc);
            }
        }
        for (; j < cnt; j++) {
            int4 e = st[wave][j];
            float w0 = h ? __int_as_float(e.z) : __int_as_float(e.y);
            float f0 = (float)feat16[(size_t)e.x * 64 + lane];
            s += w0;
            acc = fmaf(w0, f0, acc);
        }
    }
    float v = (s > 0.f) ? acc / s : 0.f;
    v = fmaxf(v + bl, 0.f);
    _Float16 hv = (_Float16)v;
    ahi[(size_t)n * 64 + lane] = hv;
    alo[(size_t)n * 64 + lane] = (_Float16)(v - (float)hv);
}

__global__ __launch_bounds__(256) void aggregate64_mean(
    const int* __restrict__ rowptr, const int* __restrict__ csrc,
    const float2* __restrict__ el2, const float2* __restrict__ er2,
    const __half2* __restrict__ feat2, const float* __restrict__ b,
    float* __restrict__ out, int N) {
    __shared__ int4 st[4][64];
    int wave = threadIdx.x >> 6, lane = threadIdx.x & 63;
    int n = rfl(blockIdx.x * 4 + wave);
    if (n >= N) return;
    float b0 = b[lane], b1 = b[64 + lane];
    int beg = rfl(rowptr[n]), end = rfl(rowptr[n + 1]);
    float2 rr = er2[n];
    float s0 = 0.f, s1 = 0.f, a0 = 0.f, a1 = 0.f;
    for (int base = beg; base < end; base += 64) {
        int idx = base + lane;
        int sv = 0; float wxv = 0.f, wyv = 0.f;
        if (idx < end) {
            sv = csrc[idx];
            float2 l = el2[sv];
            float t0 = l.x + rr.x; t0 = t0 > 0.f ? t0 : NEG_SLOPE * t0;
            float t1 = l.y + rr.y; t1 = t1 > 0.f ? t1 : NEG_SLOPE * t1;
            wxv = __expf(t0); wyv = __expf(t1);
        }
        st[wave][lane] = make_int4(sv, __float_as_int(wxv), __float_as_int(wyv), 0);
        int cnt = min(64, end - base);
        int j = 0;
        for (; j + 7 < cnt; j += 8) {
            float2 fv[8]; float wxs[8], wys[8];
#pragma unroll
            for (int u = 0; u < 8; u++) {
                int4 e = st[wave][j + u];
                wxs[u] = __int_as_float(e.y);
                wys[u] = __int_as_float(e.z);
                fv[u] = __half22float2(feat2[(size_t)e.x * 64 + lane]);
            }
#pragma unroll
            for (int u = 0; u < 8; u++) {
                s0 += wxs[u]; s1 += wys[u];
                a0 = fmaf(wxs[u], fv[u].x, a0);
                a1 = fmaf(wys[u], fv[u].y, a1);
            }
        }
        for (; j < cnt; j++) {
            int4 e = st[wave][j];
            float wx0 = __int_as_float(e.y), wy0 = __int_as_float(e.z);
            float2 f0 = __half22float2(feat2[(size_t)e.x * 64 + lane]);
            s0 += wx0; s1 += wy0;
            a0 = fmaf(wx0, f0.x, a0); a1 = fmaf(wy0, f0.y, a1);
        }
    }
    float v0 = (s0 > 0.f) ? a0 / s0 : 0.f;
    float v1 = (s1 > 0.f) ? a1 / s1 : 0.f;
    out[(size_t)n * 64 + lane] = 0.5f * ((v0 + b0) + (v1 + b1));
}

// ---------------- launcher ----------------

extern "C" void kernel_launch(void* const* d_in, const int* in_sizes, int n_in,
                              void* d_out, int out_size, void* d_ws, size_t ws_size,
                              hipStream_t stream) {
    const float* x   = (const float*)d_in[0];
    const int*   src = (const int*)d_in[1];
    const int*   dst = (const int*)d_in[2];
    const float* W0  = (const float*)d_in[3];
    const float* al0 = (const float*)d_in[4];
    const float* ar0 = (const float*)d_in[5];
    const float* b0  = (const float*)d_in[6];
    const float* W1  = (const float*)d_in[7];
    const float* al1 = (const float*)d_in[8];
    const float* ar1 = (const float*)d_in[9];
    const float* b1  = (const float*)d_in[10];
    const float* W2  = (const float*)d_in[11];
    const float* al2 = (const float*)d_in[12];
    const float* ar2 = (const float*)d_in[13];
    const float* b2  = (const float*)d_in[14];
    float* out = (float*)d_out;

    const int N = NNODES;
    const int E = in_sizes[1];

    char* p = (char*)d_ws;
    auto alloc = [&](size_t bytes) {
        void* r = (void*)p;
        p += (bytes + 255) & ~(size_t)255;
        return r;
    };
    int*    bhist    = (int*)alloc((size_t)NBKT * 4);
    int*    bbase    = (int*)alloc((size_t)NBKT * 4);
    int*    bcursor  = (int*)alloc((size_t)NBKT * 16 * 4);
    int*    rowptr   = (int*)alloc((size_t)(N + 1) * 4);
    int2*   ebuf     = (int2*)alloc((size_t)E * 8);
    int*    csrc     = (int*)alloc((size_t)E * 4);
    float2* el2      = (float2*)alloc((size_t)N * 8);
    float2* er2      = (float2*)alloc((size_t)N * 8);
    _Float16* ahi    = (_Float16*)alloc((size_t)N * 128 * 2);
    _Float16* alo    = (_Float16*)alloc((size_t)N * 128 * 2);
    void*   featbuf  = alloc((size_t)N * 64 * 4);   // fp16[N][64] or half2[N][64]
    _Float16* Wp0    = (_Float16*)alloc(4 * 4 * 64 * 8 * 2);
    _Float16* Wp1    = (_Float16*)alloc(4 * 2 * 64 * 8 * 2);
    _Float16* Wp2    = (_Float16*)alloc(8 * 2 * 64 * 8 * 2);
    _Float16* feat16 = (_Float16*)featbuf;
    __half2*  feat2  = (__half2*)featbuf;

    // CSR build (graph is layer-invariant)
    hipMemsetAsync(bhist, 0, (size_t)NBKT * 4, stream);
    bucket_hist<<<512, 256, 0, stream>>>(dst, bhist, E);
    scan_buckets<<<1, 256, 0, stream>>>(bhist, bbase, bcursor);
    int pb = (E + 1024 * PEPT - 1) / (1024 * PEPT);
    partition_edges<<<pb, 1024, 0, stream>>>(src, dst, bcursor, ebuf, E);
    local_sort<<<NBKT, 256, 0, stream>>>(ebuf, bbase, rowptr, csrc, N, E);

    // weight packing + input split
    pack_w3<<<10, 256, 0, stream>>>(W0, Wp0, W1, Wp1, W2, Wp2);
    int t4 = N * 128 / 4;
    split_fp16<<<(t4 + 255) / 256, 256, 0, stream>>>(x, ahi, alo, t4);

    int nb4 = (N + 3) / 4;               // aggregation: one wave per node
    int gb = (N / 16 + 3) / 4;           // gemm: one wave per 16-row tile

    // layer 0: IN=128 -> H2xD32
    gemm_mfma<128, 64, false><<<gb, 256, 0, stream>>>(ahi, alo, Wp0, al0, ar0, featbuf, el2, er2, N);
    aggregate32<<<nb4, 256, 0, stream>>>(rowptr, csrc, el2, er2, feat16, b0, ahi, alo, N);

    // layer 1: 64 -> H2xD32
    gemm_mfma<64, 64, false><<<gb, 256, 0, stream>>>(ahi, alo, Wp1, al1, ar1, featbuf, el2, er2, N);
    aggregate32<<<nb4, 256, 0, stream>>>(rowptr, csrc, el2, er2, feat16, b1, ahi, alo, N);

    // layer 2: 64 -> H2xD64, mean over heads (interleaved half2 feat)
    gemm_mfma<64, 128, true><<<gb, 256, 0, stream>>>(ahi, alo, Wp2, al2, ar2, featbuf, el2, er2, N);
    aggregate64_mean<<<nb4, 256, 0, stream>>>(rowptr, csrc, el2, er2, feat2, b2, out, N);
}

// Round 11
// 257.410 us; speedup vs baseline: 1.6300x; 1.0333x over previous
//
#include <hip/hip_runtime.h>
#include <hip/hip_bf16.h>
#include <hip/hip_fp16.h>

#define NNODES 50000
#define NEG_SLOPE 0.2f
#define BKT_SHIFT 8
#define NBKT ((NNODES + 255) >> 8)   // 196 buckets of 256 dsts
#define PEPT 8                        // partition: edges per thread

typedef _Float16 half8 __attribute__((ext_vector_type(8)));
typedef float v4f __attribute__((ext_vector_type(4)));

__device__ __forceinline__ int rfl(int v) { return __builtin_amdgcn_readfirstlane(v); }

// ---------------- W packing (fused into bucket_hist launch) ----------------
__device__ __forceinline__ void pack_one(const float* W, _Float16* Wp, int K, int C, int tid) {
    int KC = K / 32;
    int l = tid & 63;
    int kc = (tid >> 6) % KC;
    int t = tid / (KC * 64);
    int cc = l & 15, q = l >> 4;
    half8 b;
#pragma unroll
    for (int j = 0; j < 8; j++)
        b[j] = (_Float16)W[(size_t)(kc * 32 + q * 8 + j) * C + t * 16 + cc];
    *(half8*)(Wp + (size_t)tid * 8) = b;
}

// blocks [0,512): per-bucket histogram (LDS privatized, int4 edge reads)
// blocks [512, 522): pack the three weight matrices into MFMA B order
__global__ void bucket_hist_pack(const int* __restrict__ dst, int* __restrict__ bhist, int E,
                                 const float* __restrict__ W0, _Float16* __restrict__ Wp0,
                                 const float* __restrict__ W1, _Float16* __restrict__ Wp1,
                                 const float* __restrict__ W2, _Float16* __restrict__ Wp2) {
    if (blockIdx.x >= 512) {
        int tid = (blockIdx.x - 512) * 256 + threadIdx.x;
        const int t0 = 4 * 4 * 64, t1 = 4 * 2 * 64, t2 = 8 * 2 * 64;
        if (tid < t0) pack_one(W0, Wp0, 128, 64, tid);
        else if (tid < t0 + t1) pack_one(W1, Wp1, 64, 64, tid - t0);
        else if (tid < t0 + t1 + t2) pack_one(W2, Wp2, 64, 128, tid - t0 - t1);
        return;
    }
    __shared__ int lh[NBKT];
    for (int i = threadIdx.x; i < NBKT; i += 256) lh[i] = 0;
    __syncthreads();
    const int4* d4 = (const int4*)dst;
    int E4 = E >> 2;
    for (int i = blockIdx.x * 256 + threadIdx.x; i < E4; i += 512 * 256) {
        int4 d = d4[i];
        atomicAdd(&lh[d.x >> BKT_SHIFT], 1);
        atomicAdd(&lh[d.y >> BKT_SHIFT], 1);
        atomicAdd(&lh[d.z >> BKT_SHIFT], 1);
        atomicAdd(&lh[d.w >> BKT_SHIFT], 1);
    }
    if (blockIdx.x == 0 && threadIdx.x < (E & 3))
        atomicAdd(&lh[dst[(E4 << 2) + threadIdx.x] >> BKT_SHIFT], 1);
    __syncthreads();
    for (int i = threadIdx.x; i < NBKT; i += 256)
        if (lh[i]) atomicAdd(&bhist[i], lh[i]);
}

// exclusive scan of 196 bucket counts -> bbase; init 64B-padded cursors
__global__ void scan_buckets(const int* __restrict__ bhist, int* __restrict__ bbase,
                             int* __restrict__ bcursor) {
    __shared__ int buf[256];
    int t = threadIdx.x;
    int v = (t < NBKT) ? bhist[t] : 0;
    buf[t] = v;
    __syncthreads();
    for (int off = 1; off < 256; off <<= 1) {
        int x = (t >= off) ? buf[t - off] : 0;
        __syncthreads();
        buf[t] += x;
        __syncthreads();
    }
    if (t < NBKT) { int e = buf[t] - v; bbase[t] = e; bcursor[t * 16] = e; }
}

// Block-privatized partition: LDS histogram gives in-block rank; ONE global
// atomic per (bucket, block) reserves a contiguous run; pass 2 fills it.
__global__ __launch_bounds__(1024) void partition_edges(
    const int* __restrict__ src, const int* __restrict__ dst,
    int* __restrict__ bcursor, int2* __restrict__ ebuf, int E) {
    __shared__ int hist[NBKT];
    __shared__ int gbase[NBKT];
    int t = threadIdx.x;
    for (int i = t; i < NBKT; i += 1024) hist[i] = 0;
    __syncthreads();
    int base = blockIdx.x * 1024 * PEPT;
    int sreg[PEPT], dreg[PEPT], rreg[PEPT], breg[PEPT];
#pragma unroll
    for (int k = 0; k < PEPT; k++) {
        int i = base + k * 1024 + t;
        if (i < E) {
            sreg[k] = src[i];
            dreg[k] = dst[i];
            breg[k] = dreg[k] >> BKT_SHIFT;
            rreg[k] = atomicAdd(&hist[breg[k]], 1);
        } else {
            breg[k] = -1;
        }
    }
    __syncthreads();
    for (int i = t; i < NBKT; i += 1024)
        if (hist[i]) gbase[i] = atomicAdd(&bcursor[i * 16], hist[i]);
    __syncthreads();
#pragma unroll
    for (int k = 0; k < PEPT; k++) {
        if (breg[k] >= 0)
            ebuf[(size_t)(gbase[breg[k]] + rreg[k])] = make_int2(sreg[k], dreg[k]);
    }
}

// one block per bucket: degree count in LDS, in-block scan -> rowptr slice,
// then place edges (csrc) by LDS cursors.
__global__ __launch_bounds__(256) void local_sort(const int2* __restrict__ ebuf,
                                                  const int* __restrict__ bbase,
                                                  int* __restrict__ rowptr,
                                                  int* __restrict__ csrc, int N, int E) {
    __shared__ int lcnt[256], lrow[256], ws[4];
    int b = blockIdx.x;
    int d0 = b << BKT_SHIFT;
    int t = threadIdx.x;
    int base = bbase[b];
    int endE = (b + 1 < NBKT) ? bbase[b + 1] : E;
    lcnt[t] = 0;
    __syncthreads();
    for (int i = base + t; i < endE; i += 256)
        atomicAdd(&lcnt[ebuf[i].y - d0], 1);
    __syncthreads();
    int v = lcnt[t];
    int lane = t & 63;
    int x = v;
#pragma unroll
    for (int m = 1; m < 64; m <<= 1) {
        int y = __shfl_up(x, m, 64);
        if (lane >= m) x += y;
    }
    if (lane == 63) ws[t >> 6] = x;
    __syncthreads();
    int w = t >> 6, waveoff = 0;
#pragma unroll
    for (int k = 0; k < 4; k++) if (k < w) waveoff += ws[k];
    int excl = base + waveoff + x - v;
    lrow[t] = excl;
    int d = d0 + t;
    if (d < N) rowptr[d] = excl;
    if (d == N) rowptr[N] = excl;
    lcnt[t] = 0;
    __syncthreads();
    for (int i = base + t; i < endE; i += 256) {
        int2 e = ebuf[i];
        int ld = e.y - d0;
        int p = lrow[ld] + atomicAdd(&lcnt[ld], 1);
        csrc[p] = e.x;
    }
}

// ---------------- MFMA GEMM + attention logits ----------------
// D = (Ahi+Alo) @ W. One wave per 16-row m-tile, all C columns.
// gfx950 16x16x32 layouts: A[m=lane&15][k=(lane>>4)*8+j],
// B[k=(lane>>4)*8+j][n=lane&15], C/D: col=lane&15, row=(lane>>4)*4+reg.
// AFP32: A is fp32; hi/lo split done in-register (same arithmetic as split_fp16).
template <int K, int C, bool INTERLEAVE, bool AFP32>
__global__ __launch_bounds__(256) void gemm_mfma(
    const void* __restrict__ Ahi_, const void* __restrict__ Alo_,
    const _Float16* __restrict__ Wp,
    const float* __restrict__ AL, const float* __restrict__ AR,
    void* __restrict__ featout, float2* __restrict__ el2, float2* __restrict__ er2,
    int N) {
    constexpr int KC = K / 32;
    constexpr int NT = C / 16;
    int wave = threadIdx.x >> 6, lane = threadIdx.x & 63;
    int mtile = blockIdx.x * 4 + wave;
    if (mtile * 16 >= N) return;
    int m0 = mtile * 16;
    int c = lane & 15, q = lane >> 4;

    v4f acc[NT];
#pragma unroll
    for (int t = 0; t < NT; t++) acc[t] = (v4f){0.f, 0.f, 0.f, 0.f};

    const size_t arow = (size_t)(m0 + c) * K + q * 8;
#pragma unroll
    for (int kc = 0; kc < KC; kc++) {
        half8 ah, av;
        if constexpr (AFP32) {
            const float* xr = (const float*)Ahi_ + arow + kc * 32;
            float4 f0 = *(const float4*)xr;
            float4 f1 = *(const float4*)(xr + 4);
            float fv[8] = {f0.x, f0.y, f0.z, f0.w, f1.x, f1.y, f1.z, f1.w};
#pragma unroll
            for (int j = 0; j < 8; j++) {
                ah[j] = (_Float16)fv[j];
                av[j] = (_Float16)(fv[j] - (float)ah[j]);
            }
        } else {
            ah = *(const half8*)((const _Float16*)Ahi_ + arow + kc * 32);
            av = *(const half8*)((const _Float16*)Alo_ + arow + kc * 32);
        }
#pragma unroll
        for (int t = 0; t < NT; t++) {
            half8 b = *(const half8*)(Wp + ((size_t)(t * KC + kc) * 64 + lane) * 8);
            acc[t] = __builtin_amdgcn_mfma_f32_16x16x32_f16(ah, b, acc[t], 0, 0, 0);
            acc[t] = __builtin_amdgcn_mfma_f32_16x16x32_f16(av, b, acc[t], 0, 0, 0);
        }
    }

    if (!INTERLEAVE) {
        _Float16* f16 = (_Float16*)featout;
#pragma unroll
        for (int t = 0; t < NT; t++)
#pragma unroll
            for (int r = 0; r < 4; r++) {
                int row = m0 + q * 4 + r;
                f16[(size_t)row * C + t * 16 + c] = (_Float16)acc[t][r];
            }
    } else {
        __half2* f2 = (__half2*)featout;
#pragma unroll
        for (int t = 0; t < NT / 2; t++)
#pragma unroll
            for (int r = 0; r < 4; r++) {
                int row = m0 + q * 4 + r;
                f2[(size_t)row * (C / 2) + t * 16 + c] =
                    __floats2half2_rn(acc[t][r], acc[t + NT / 2][r]);
            }
    }

    float alv[NT], arv[NT];
#pragma unroll
    for (int t = 0; t < NT; t++) { alv[t] = AL[t * 16 + c]; arv[t] = AR[t * 16 + c]; }
#pragma unroll
    for (int r = 0; r < 4; r++) {
        float l0 = 0.f, l1 = 0.f, r0 = 0.f, r1 = 0.f;
#pragma unroll
        for (int t = 0; t < NT; t++) {
            float v = acc[t][r];
            if (t < NT / 2) { l0 = fmaf(v, alv[t], l0); r0 = fmaf(v, arv[t], r0); }
            else            { l1 = fmaf(v, alv[t], l1); r1 = fmaf(v, arv[t], r1); }
        }
#pragma unroll
        for (int m = 1; m < 16; m <<= 1) {
            l0 += __shfl_xor(l0, m, 64);
            l1 += __shfl_xor(l1, m, 64);
            r0 += __shfl_xor(r0, m, 64);
            r1 += __shfl_xor(r1, m, 64);
        }
        if (c == 0) {
            int row = m0 + q * 4 + r;
            el2[row] = make_float2(l0, l1);
            er2[row] = make_float2(r0, r1);
        }
    }
}

// ---------------- Aggregation ----------------
// agg32: per-head staging arrays stA={src,wx}, stB={src,wy}. Reader lane picks
// its head's array (2 distinct addrs per wave = free 2-way) and reads TWO edges
// per ds_read_b128 — DS cost/edge halves vs int4 staging. Weights stay fp32.
// Intra-wave LDS RAW is safe: one wave's DS ops process in program order.
__global__ __launch_bounds__(256) void aggregate32(
    const int* __restrict__ rowptr, const int* __restrict__ csrc,
    const float2* __restrict__ el2, const float2* __restrict__ er2,
    const _Float16* __restrict__ feat16, const float* __restrict__ b,
    _Float16* __restrict__ ahi, _Float16* __restrict__ alo, int N) {
    __shared__ int2 stA[4][64], stB[4][64];
    int wave = threadIdx.x >> 6, lane = threadIdx.x & 63, h = lane >> 5;
    int n = rfl(blockIdx.x * 4 + wave);
    if (n >= N) return;
    float bl = b[lane];
    int beg = rfl(rowptr[n]), end = rfl(rowptr[n + 1]);
    float2 rr = er2[n];
    const int2* stH = h ? stB[wave] : stA[wave];
    float s = 0.f, acc = 0.f;
    for (int base = beg; base < end; base += 64) {
        int idx = base + lane;
        int sv = 0; float wxv = 0.f, wyv = 0.f;
        if (idx < end) {
            sv = csrc[idx];
            float2 l = el2[sv];
            float t0 = l.x + rr.x; t0 = t0 > 0.f ? t0 : NEG_SLOPE * t0;
            float t1 = l.y + rr.y; t1 = t1 > 0.f ? t1 : NEG_SLOPE * t1;
            wxv = __expf(t0); wyv = __expf(t1);
        }
        stA[wave][lane] = make_int2(sv, __float_as_int(wxv));
        stB[wave][lane] = make_int2(sv, __float_as_int(wyv));
        int cnt = min(64, end - base);
        int j = 0;
        for (; j + 7 < cnt; j += 8) {
            int4 e01 = *(const int4*)(stH + j);
            int4 e23 = *(const int4*)(stH + j + 2);
            int4 e45 = *(const int4*)(stH + j + 4);
            int4 e67 = *(const int4*)(stH + j + 6);
            float f0 = (float)feat16[(size_t)e01.x * 64 + lane];
            float f1 = (float)feat16[(size_t)e01.z * 64 + lane];
            float f2 = (float)feat16[(size_t)e23.x * 64 + lane];
            float f3 = (float)feat16[(size_t)e23.z * 64 + lane];
            float f4 = (float)feat16[(size_t)e45.x * 64 + lane];
            float f5 = (float)feat16[(size_t)e45.z * 64 + lane];
            float f6 = (float)feat16[(size_t)e67.x * 64 + lane];
            float f7 = (float)feat16[(size_t)e67.z * 64 + lane];
            float w0 = __int_as_float(e01.y), w1 = __int_as_float(e01.w);
            float w2 = __int_as_float(e23.y), w3 = __int_as_float(e23.w);
            float w4 = __int_as_float(e45.y), w5 = __int_as_float(e45.w);
            float w6 = __int_as_float(e67.y), w7 = __int_as_float(e67.w);
            s += ((w0 + w1) + (w2 + w3)) + ((w4 + w5) + (w6 + w7));
            acc = fmaf(w0, f0, acc);
            acc = fmaf(w1, f1, acc);
            acc = fmaf(w2, f2, acc);
            acc = fmaf(w3, f3, acc);
            acc = fmaf(w4, f4, acc);
            acc = fmaf(w5, f5, acc);
            acc = fmaf(w6, f6, acc);
            acc = fmaf(w7, f7, acc);
        }
        for (; j < cnt; j++) {
            int2 e = stH[j];
            float w0 = __int_as_float(e.y);
            float f0 = (float)feat16[(size_t)e.x * 64 + lane];
            s += w0;
            acc = fmaf(w0, f0, acc);
        }
    }
    float v = (s > 0.f) ? acc / s : 0.f;
    v = fmaxf(v + bl, 0.f);
    _Float16 hv = (_Float16)v;
    ahi[(size_t)n * 64 + lane] = hv;
    alo[(size_t)n * 64 + lane] = (_Float16)(v - (float)hv);
}

// agg64: each lane needs BOTH head weights -> keep int4 {src,wx,wy} staging.
__global__ __launch_bounds__(256) void aggregate64_mean(
    const int* __restrict__ rowptr, const int* __restrict__ csrc,
    const float2* __restrict__ el2, const float2* __restrict__ er2,
    const __half2* __restrict__ feat2, const float* __restrict__ b,
    float* __restrict__ out, int N) {
    __shared__ int4 st[4][64];
    int wave = threadIdx.x >> 6, lane = threadIdx.x & 63;
    int n = rfl(blockIdx.x * 4 + wave);
    if (n >= N) return;
    float b0 = b[lane], b1 = b[64 + lane];
    int beg = rfl(rowptr[n]), end = rfl(rowptr[n + 1]);
    float2 rr = er2[n];
    float s0 = 0.f, s1 = 0.f, a0 = 0.f, a1 = 0.f;
    for (int base = beg; base < end; base += 64) {
        int idx = base + lane;
        int sv = 0; float wxv = 0.f, wyv = 0.f;
        if (idx < end) {
            sv = csrc[idx];
            float2 l = el2[sv];
            float t0 = l.x + rr.x; t0 = t0 > 0.f ? t0 : NEG_SLOPE * t0;
            float t1 = l.y + rr.y; t1 = t1 > 0.f ? t1 : NEG_SLOPE * t1;
            wxv = __expf(t0); wyv = __expf(t1);
        }
        st[wave][lane] = make_int4(sv, __float_as_int(wxv), __float_as_int(wyv), 0);
        int cnt = min(64, end - base);
        int j = 0;
        for (; j + 7 < cnt; j += 8) {
            float2 fv[8]; float wxs[8], wys[8];
#pragma unroll
            for (int u = 0; u < 8; u++) {
                int4 e = st[wave][j + u];
                wxs[u] = __int_as_float(e.y);
                wys[u] = __int_as_float(e.z);
                fv[u] = __half22float2(feat2[(size_t)e.x * 64 + lane]);
            }
#pragma unroll
            for (int u = 0; u < 8; u++) {
                s0 += wxs[u]; s1 += wys[u];
                a0 = fmaf(wxs[u], fv[u].x, a0);
                a1 = fmaf(wys[u], fv[u].y, a1);
            }
        }
        for (; j < cnt; j++) {
            int4 e = st[wave][j];
            float wx0 = __int_as_float(e.y), wy0 = __int_as_float(e.z);
            float2 f0 = __half22float2(feat2[(size_t)e.x * 64 + lane]);
            s0 += wx0; s1 += wy0;
            a0 = fmaf(wx0, f0.x, a0); a1 = fmaf(wy0, f0.y, a1);
        }
    }
    float v0 = (s0 > 0.f) ? a0 / s0 : 0.f;
    float v1 = (s1 > 0.f) ? a1 / s1 : 0.f;
    out[(size_t)n * 64 + lane] = 0.5f * ((v0 + b0) + (v1 + b1));
}

// ---------------- launcher ----------------

extern "C" void kernel_launch(void* const* d_in, const int* in_sizes, int n_in,
                              void* d_out, int out_size, void* d_ws, size_t ws_size,
                              hipStream_t stream) {
    const float* x   = (const float*)d_in[0];
    const int*   src = (const int*)d_in[1];
    const int*   dst = (const int*)d_in[2];
    const float* W0  = (const float*)d_in[3];
    const float* al0 = (const float*)d_in[4];
    const float* ar0 = (const float*)d_in[5];
    const float* b0  = (const float*)d_in[6];
    const float* W1  = (const float*)d_in[7];
    const float* al1 = (const float*)d_in[8];
    const float* ar1 = (const float*)d_in[9];
    const float* b1  = (const float*)d_in[10];
    const float* W2  = (const float*)d_in[11];
    const float* al2 = (const float*)d_in[12];
    const float* ar2 = (const float*)d_in[13];
    const float* b2  = (const float*)d_in[14];
    float* out = (float*)d_out;

    const int N = NNODES;
    const int E = in_sizes[1];

    char* p = (char*)d_ws;
    auto alloc = [&](size_t bytes) {
        void* r = (void*)p;
        p += (bytes + 255) & ~(size_t)255;
        return r;
    };
    int*    bhist    = (int*)alloc((size_t)NBKT * 4);
    int*    bbase    = (int*)alloc((size_t)NBKT * 4);
    int*    bcursor  = (int*)alloc((size_t)NBKT * 16 * 4);
    int*    rowptr   = (int*)alloc((size_t)(N + 1) * 4);
    int2*   ebuf     = (int2*)alloc((size_t)E * 8);
    int*    csrc     = (int*)alloc((size_t)E * 4);
    float2* el2      = (float2*)alloc((size_t)N * 8);
    float2* er2      = (float2*)alloc((size_t)N * 8);
    _Float16* ahi    = (_Float16*)alloc((size_t)N * 64 * 2);
    _Float16* alo    = (_Float16*)alloc((size_t)N * 64 * 2);
    void*   featbuf  = alloc((size_t)N * 64 * 4);   // fp16[N][64] or half2[N][64]
    _Float16* Wp0    = (_Float16*)alloc(4 * 4 * 64 * 8 * 2);
    _Float16* Wp1    = (_Float16*)alloc(4 * 2 * 64 * 8 * 2);
    _Float16* Wp2    = (_Float16*)alloc(8 * 2 * 64 * 8 * 2);
    _Float16* feat16 = (_Float16*)featbuf;
    __half2*  feat2  = (__half2*)featbuf;

    // CSR build (graph is layer-invariant) + weight packing (piggy-backed)
    hipMemsetAsync(bhist, 0, (size_t)NBKT * 4, stream);
    bucket_hist_pack<<<522, 256, 0, stream>>>(dst, bhist, E, W0, Wp0, W1, Wp1, W2, Wp2);
    scan_buckets<<<1, 256, 0, stream>>>(bhist, bbase, bcursor);
    int pb = (E + 1024 * PEPT - 1) / (1024 * PEPT);
    partition_edges<<<pb, 1024, 0, stream>>>(src, dst, bcursor, ebuf, E);
    local_sort<<<NBKT, 256, 0, stream>>>(ebuf, bbase, rowptr, csrc, N, E);

    int nb4 = (N + 3) / 4;               // aggregation: one wave per node
    int gb = (N / 16 + 3) / 4;           // gemm: one wave per 16-row tile

    // layer 0: IN=128 -> H2xD32 (A = x fp32, split in-register)
    gemm_mfma<128, 64, false, true><<<gb, 256, 0, stream>>>(x, nullptr, Wp0, al0, ar0, featbuf, el2, er2, N);
    aggregate32<<<nb4, 256, 0, stream>>>(rowptr, csrc, el2, er2, feat16, b0, ahi, alo, N);

    // layer 1: 64 -> H2xD32
    gemm_mfma<64, 64, false, false><<<gb, 256, 0, stream>>>(ahi, alo, Wp1, al1, ar1, featbuf, el2, er2, N);
    aggregate32<<<nb4, 256, 0, stream>>>(rowptr, csrc, el2, er2, feat16, b1, ahi, alo, N);

    // layer 2: 64 -> H2xD64, mean over heads (interleaved half2 feat)
    gemm_mfma<64, 128, true, false><<<gb, 256, 0, stream>>>(ahi, alo, Wp2, al2, ar2, featbuf, el2, er2, N);
    aggregate64_mean<<<nb4, 256, 0, stream>>>(rowptr, csrc, el2, er2, feat2, b2, out, N);
}